// Round 11
// baseline (317.820 us; speedup 1.0000x reference)
//
#include <hip/hip_runtime.h>

#define M_ACT 4000
#define NNODE 20000
#define NE 150000
#define DD 128
#define NT_E 586   // ceil(NE/256), edge kernel: 256 rank-rows per block tile
#define NB_N2 313  // ceil(NNODE/64)
#define HB 587     // ceil(NE/256), hist/scatter blocks
#define AB 63      // ceil(M_ACT/64), 64-row units
#define AB16 250   // M_ACT/16, 16-row actor blocks (exact)
#define ASTR 136   // actor LDS row stride (shorts)
#define WSTR 72    // wblob chunk row stride (shorts)
#define BSTR 136   // transpose buffer row stride (shorts): 68 words == 4 mod 32 -> conflict-free b128

typedef __attribute__((ext_vector_type(8))) short bh8;
typedef __attribute__((ext_vector_type(4))) float vf4;

#define MFMA16(a, b, c) __builtin_amdgcn_mfma_f32_16x16x32_bf16((a), (b), (c), 0, 0, 0)
#define LGKM0() __asm__ volatile("s_waitcnt lgkmcnt(0)" ::: "memory")

__device__ __forceinline__ unsigned short f2bf(float f) {
    unsigned u = __float_as_uint(f);
    u = (u + 0x7fffu + ((u >> 16) & 1u)) >> 16;
    return (unsigned short)u;
}
__device__ __forceinline__ float bf2f(unsigned short s) {
    return __uint_as_float(((unsigned)s) << 16);
}

// GroupNorm stats from one 16x128 MFMA C-layout row-tile (8 col-tiles).
__device__ __forceinline__ void gn_stats8(const vf4* acc, float* mean, float* rs) {
    float s[4], q[4];
#pragma unroll
    for (int i = 0; i < 4; i++) {
        float a = 0.f, b = 0.f;
#pragma unroll
        for (int t = 0; t < 8; t++) { float v = acc[t][i]; a += v; b += v * v; }
        s[i] = a; q[i] = b;
    }
#pragma unroll
    for (int m = 1; m < 16; m <<= 1) {
#pragma unroll
        for (int i = 0; i < 4; i++) {
            s[i] += __shfl_xor(s[i], m, 64);
            q[i] += __shfl_xor(q[i], m, 64);
        }
    }
#pragma unroll
    for (int i = 0; i < 4; i++) {
        float mu = s[i] * (1.0f / 128.0f);
        float var = q[i] * (1.0f / 128.0f) - mu * mu;
        mean[i] = mu;
        rs[i] = rsqrtf(var + 1e-5f);
    }
}

template <bool RELU>
__device__ __forceinline__ void gn_to_lds(const vf4* acc, const float* __restrict__ gw,
                                          const float* __restrict__ gb, unsigned short* sm,
                                          int stride, int cb, int r0, int grp, int lm) {
    float mean[4], rs[4];
    gn_stats8(acc, mean, rs);
#pragma unroll
    for (int t = 0; t < 8; t++) {
        int c = 16 * t + lm;
        float w = gw[c], b = gb[c];
#pragma unroll
        for (int i = 0; i < 4; i++) {
            float y = (acc[t][i] - mean[i]) * rs[i] * w + b;
            if (RELU) y = fmaxf(y, 0.0f);
            sm[(r0 + grp * 4 + i) * stride + cb + c] = f2bf(y);
        }
    }
}

__device__ __forceinline__ void load_chunk(const unsigned short* __restrict__ src,
                                           unsigned short* dst, int tid) {
    for (int idx = tid; idx < 1152; idx += 256) {
        *(uint4*)&dst[idx * 8] = *(const uint4*)&src[idx * 8];
    }
}

// convert one 128x64 weight chunk (f32, row-major, K cols, col-block kc) into
// the WSTR-padded bf16 LDS layout — identical output to convert+load_chunk.
__device__ __forceinline__ void conv_chunk(const float* __restrict__ src, int K, int kc,
                                           unsigned short* dst, int tid) {
    for (int idx = tid; idx < 9216; idx += 256) {
        int n = idx / 72, kk = idx - n * 72;
        float v = (kk < 64) ? src[n * K + kc * 64 + kk] : 0.f;
        dst[idx] = f2bf(v);
    }
}

// 16-row GEMM pass, B-fragments streamed directly from the L2-hot wblob.
__device__ __forceinline__ void gemm16(const unsigned short* smA,
                                       const unsigned short* __restrict__ w2ch, vf4* acc,
                                       int grp, int lm) {
#pragma unroll
    for (int ks = 0; ks < 4; ks++) {
        bh8 a = *(const bh8*)&smA[lm * ASTR + ks * 32 + grp * 8];
#pragma unroll
        for (int t = 0; t < 8; t++) {
            bh8 b = *(const bh8*)&w2ch[(ks >> 1) * 9216 + (16 * t + lm) * WSTR +
                                       (ks & 1) * 32 + grp * 8];
            acc[t] = MFMA16(a, b, acc[t]);
        }
    }
}

// stage 16 rows of f32 src (rows m0..m0+15, all < M_ACT) into smA as bf16
__device__ __forceinline__ void stage16(const float* __restrict__ src, int m0,
                                        unsigned short* smA, int lane) {
    for (int idx = lane; idx < 16 * 32; idx += 64) {
        int r = idx >> 5, q = idx & 31;
        const float4 v = *(const float4*)(src + (size_t)(m0 + r) * DD + q * 4);
        unsigned lo = (unsigned)f2bf(v.x) | ((unsigned)f2bf(v.y) << 16);
        unsigned hi2 = (unsigned)f2bf(v.z) | ((unsigned)f2bf(v.w) << 16);
        *(uint2*)&smA[r * ASTR + q * 4] = make_uint2(lo, hi2);
    }
}

// =====================  SETUP: hist + convert + Q2(L0) + Aa(L0)  ==============
// Q2/Aa self-convert their weights from f32 (no dependence on the convert
// blocks in the same launch). All four segments are mutually independent.
__global__ __launch_bounds__(256, 2) void setup_kernel(
    const int* __restrict__ hi, int* __restrict__ hist, const float* __restrict__ Wd2,
    const float* __restrict__ Wq, const float* __restrict__ Wc1,
    const float* __restrict__ Wc2, const float* __restrict__ Wa,
    const float* __restrict__ Wl, unsigned short* __restrict__ wblob,
    const float* __restrict__ agts, const float* __restrict__ gnq_w,
    const float* __restrict__ gnq_b, float* __restrict__ Q2, float* __restrict__ Aa) {
    __shared__ unsigned short smA[64 * ASTR];
    __shared__ unsigned short smW[128 * WSTR];
    const int tid = threadIdx.x;
    int b = blockIdx.x;
    if (b < HB) {  // ---- hist
        int e = b * 256 + tid;
        if (e < NE) atomicAdd(&hist[hi[e]], 1);
        return;
    }
    b -= HB;
    if (b < 32) {  // ---- weight convert -> wblob
        int ci = b;
        int l = ci >> 4, r = ci & 15;
        const float* src;
        int kc, K;
        if (r < 2)       { src = Wd2 + l * 16384; kc = r;      K = 128; }
        else if (r < 4)  { src = Wq  + l * 16384; kc = r - 2;  K = 128; }
        else if (r < 10) { src = Wc1 + l * 49152; kc = r - 4;  K = 384; }
        else if (r < 12) { src = Wc2 + l * 16384; kc = r - 10; K = 128; }
        else if (r < 14) { src = Wa  + l * 16384; kc = r - 12; K = 128; }
        else             { src = Wl  + l * 16384; kc = r - 14; K = 128; }
        unsigned short* dst = wblob + (size_t)ci * 9216;
        for (int idx = tid; idx < 9216; idx += 256) {
            int n = idx / 72, kk = idx - n * 72;
            float v = (kk < 64) ? src[n * K + kc * 64 + kk] : 0.f;
            dst[idx] = f2bf(v);
        }
        return;
    }
    b -= 32;
    const int wave = tid >> 6, lane = tid & 63, grp = lane >> 4, lm = lane & 15;
    const int r0 = wave * 16;
    const int arow = r0 + lm;
    const int m0 = (b < AB ? b : b - AB) * 64;
    for (int idx = tid; idx < 64 * 32; idx += 256) {
        int r = idx >> 5, q = idx & 31;
        int m = m0 + r;
        if (m >= M_ACT) m = 0;
        const float4 v = *(const float4*)(agts + (size_t)m * DD + q * 4);
        unsigned lo = (unsigned)f2bf(v.x) | ((unsigned)f2bf(v.y) << 16);
        unsigned hi2 = (unsigned)f2bf(v.z) | ((unsigned)f2bf(v.w) << 16);
        *(uint2*)&smA[r * ASTR + q * 4] = make_uint2(lo, hi2);
    }
    __syncthreads();
    vf4 acc[8];
#pragma unroll
    for (int t = 0; t < 8; t++) acc[t] = (vf4){0.f, 0.f, 0.f, 0.f};
    if (b < AB) {  // ---- Q2 layer 0 (self-convert Wq, Wc1_q)
        for (int ch = 0; ch < 2; ch++) {
            conv_chunk(Wq, 128, ch, smW, tid);
            __syncthreads();
#pragma unroll
            for (int k0 = 0; k0 < 64; k0 += 32) {
                bh8 a = *(const bh8*)&smA[arow * ASTR + ch * 64 + k0 + grp * 8];
#pragma unroll
                for (int t = 0; t < 8; t++) {
                    bh8 bb = *(const bh8*)&smW[(16 * t + lm) * WSTR + k0 + grp * 8];
                    acc[t] = MFMA16(a, bb, acc[t]);
                }
            }
            __syncthreads();
        }
        gn_to_lds<true>(acc, gnq_w, gnq_b, smA, ASTR, 0, r0, grp, lm);
#pragma unroll
        for (int t = 0; t < 8; t++) acc[t] = (vf4){0.f, 0.f, 0.f, 0.f};
        for (int ch = 0; ch < 2; ch++) {
            conv_chunk(Wc1, 384, 2 + ch, smW, tid);
            __syncthreads();
#pragma unroll
            for (int k0 = 0; k0 < 64; k0 += 32) {
                bh8 a = *(const bh8*)&smA[arow * ASTR + ch * 64 + k0 + grp * 8];
#pragma unroll
                for (int t = 0; t < 8; t++) {
                    bh8 bb = *(const bh8*)&smW[(16 * t + lm) * WSTR + k0 + grp * 8];
                    acc[t] = MFMA16(a, bb, acc[t]);
                }
            }
            __syncthreads();
        }
#pragma unroll
        for (int t = 0; t < 8; t++) {
            int c = 16 * t + lm;
#pragma unroll
            for (int i = 0; i < 4; i++) {
                int m = m0 + r0 + grp * 4 + i;
                if (m < M_ACT) Q2[(size_t)m * DD + c] = acc[t][i];
            }
        }
        return;
    }
    // ---- Aa = actors @ Wa^T (layer 0, self-convert Wa)
    for (int ch = 0; ch < 2; ch++) {
        conv_chunk(Wa, 128, ch, smW, tid);
        __syncthreads();
#pragma unroll
        for (int k0 = 0; k0 < 64; k0 += 32) {
            bh8 a = *(const bh8*)&smA[arow * ASTR + ch * 64 + k0 + grp * 8];
#pragma unroll
            for (int t = 0; t < 8; t++) {
                bh8 bb = *(const bh8*)&smW[(16 * t + lm) * WSTR + k0 + grp * 8];
                acc[t] = MFMA16(a, bb, acc[t]);
            }
        }
        __syncthreads();
    }
#pragma unroll
    for (int t = 0; t < 8; t++) {
        int c = 16 * t + lm;
#pragma unroll
        for (int i = 0; i < 4; i++) {
            int m = m0 + r0 + grp * 4 + i;
            if (m < M_ACT) Aa[(size_t)m * DD + c] = acc[t][i];
        }
    }
}

__global__ void scan_kernel(const int* __restrict__ hist, int* __restrict__ cursor) {
    __shared__ int part[256];
    int t = threadIdx.x;
    int base = t * 16;
    int s = 0;
    if (base < M_ACT)
        for (int i = 0; i < 16; i++) s += hist[base + i];
    part[t] = s;
    __syncthreads();
    for (int d = 1; d < 256; d <<= 1) {
        int u = (t >= d) ? part[t - d] : 0;
        __syncthreads();
        part[t] += u;
        __syncthreads();
    }
    int excl = part[t] - s;
    if (base < M_ACT) {
        int run = excl;
        for (int i = 0; i < 16; i++) {
            cursor[base + i] = run;
            run += hist[base + i];
        }
    }
}

// =====================  MEGA1: scatter + N2(layer 0)  =========================
__global__ __launch_bounds__(256, 2) void mega1_kernel(
    const int* __restrict__ hi, const int* __restrict__ wi, int* __restrict__ cursor,
    int* __restrict__ hi_s, int* __restrict__ wi_s, const float* __restrict__ nodes,
    const unsigned short* __restrict__ wblob0, float* __restrict__ N2_0) {
    __shared__ unsigned short smA[64 * ASTR];
    __shared__ unsigned short smW[128 * WSTR];
    const int tid = threadIdx.x;
    int b = blockIdx.x;
    if (b < HB) {  // ---- scatter
        int e = b * 256 + tid;
        if (e < NE) {
            int h = hi[e];
            int p = atomicAdd(&cursor[h], 1);
            hi_s[p] = h;
            wi_s[p] = wi[e];
        }
        return;
    }
    b -= HB;  // 0..312: N2_0 = nodes @ Wc1_n^T (layer 0)
    const int wave = tid >> 6, lane = tid & 63, grp = lane >> 4, lm = lane & 15;
    const int r0 = wave * 16;
    const int arow = r0 + lm;
    const int n0 = b * 64;
    for (int idx = tid; idx < 64 * 32; idx += 256) {
        int r = idx >> 5, q = idx & 31;
        int n = n0 + r;
        if (n >= NNODE) n = 0;
        const float4 v = *(const float4*)(nodes + (size_t)n * DD + q * 4);
        unsigned lo = (unsigned)f2bf(v.x) | ((unsigned)f2bf(v.y) << 16);
        unsigned hi2 = (unsigned)f2bf(v.z) | ((unsigned)f2bf(v.w) << 16);
        *(uint2*)&smA[r * ASTR + q * 4] = make_uint2(lo, hi2);
    }
    __syncthreads();
    vf4 acc[8];
#pragma unroll
    for (int t = 0; t < 8; t++) acc[t] = (vf4){0.f, 0.f, 0.f, 0.f};
    for (int ch = 0; ch < 2; ch++) {
        load_chunk(wblob0 + (8 + ch) * 9216, smW, tid);
        __syncthreads();
#pragma unroll
        for (int k0 = 0; k0 < 64; k0 += 32) {
            bh8 a = *(const bh8*)&smA[arow * ASTR + ch * 64 + k0 + grp * 8];
#pragma unroll
            for (int t = 0; t < 8; t++) {
                bh8 bb = *(const bh8*)&smW[(16 * t + lm) * WSTR + k0 + grp * 8];
                acc[t] = MFMA16(a, bb, acc[t]);
            }
        }
        __syncthreads();
    }
#pragma unroll
    for (int t = 0; t < 8; t++) {
        int c = 16 * t + lm;
#pragma unroll
        for (int i = 0; i < 4; i++) {
            int n = n0 + r0 + grp * 4 + i;
            if (n < NNODE) N2_0[(size_t)n * DD + c] = acc[t][i];
        }
    }
}

// =====================  EDGE KERNEL (+ N2_1 tail blocks in edge0 launch)  =====
// Blocks 0..255: the proven edge path (unchanged). Blocks 256+ (only present in
// the layer-0 launch): N2_1 = nodes @ Wc1_n1^T with B streamed from the L2-hot
// wblob — they fill the edge block-drain tail instead of pre-edge serial time.
__global__ __launch_bounds__(512, 2) void edge_kernel(
    const float* __restrict__ actor_ctrs, const float* __restrict__ node_ctrs,
    const float* __restrict__ Wd1_l, const float* __restrict__ bd1_l,
    const float* __restrict__ Q2, const float* __restrict__ N2,
    const int* __restrict__ hi_s, const int* __restrict__ wi_s,
    const unsigned short* __restrict__ wblob_l,
    const float* __restrict__ gnd2_w, const float* __restrict__ gnd2_b,
    const float* __restrict__ gnc1_w, const float* __restrict__ gnc1_b,
    float* __restrict__ ssum, int* __restrict__ ctr, const float* __restrict__ nodes,
    const unsigned short* __restrict__ wblob_n1, float* __restrict__ N2out) {
    __shared__ unsigned short smW[4 * 9216];     // Wd2 k0,k1 | Wc1_d k0,k1
    __shared__ unsigned short smBuf[8][32 * BSTR];
    __shared__ float smWd1[3][128];
    __shared__ int smTile;
    if (blockIdx.x >= 256) {
        // ---- N2_1 tail block: 64 rows, 8 waves = 4 row-groups x 2 col-halves
        unsigned short* smA2 = &smBuf[0][0];
        const int tid = threadIdx.x;
        const int n0 = (blockIdx.x - 256) * 64;
        for (int idx = tid; idx < 64 * 32; idx += 512) {
            int r = idx >> 5, q = idx & 31;
            int n = n0 + r;
            if (n >= NNODE) n = 0;
            const float4 v = *(const float4*)(nodes + (size_t)n * DD + q * 4);
            unsigned lo = (unsigned)f2bf(v.x) | ((unsigned)f2bf(v.y) << 16);
            unsigned hi2 = (unsigned)f2bf(v.z) | ((unsigned)f2bf(v.w) << 16);
            *(uint2*)&smA2[r * BSTR + q * 4] = make_uint2(lo, hi2);
        }
        __syncthreads();
        const int wv = tid >> 6, lane = tid & 63, grp = lane >> 4, lm = lane & 15;
        const int rg = wv >> 1, th = wv & 1;
        vf4 acc[4];
#pragma unroll
        for (int t = 0; t < 4; t++) acc[t] = (vf4){0.f, 0.f, 0.f, 0.f};
#pragma unroll
        for (int ks = 0; ks < 4; ks++) {
            bh8 a = *(const bh8*)&smA2[(rg * 16 + lm) * BSTR + ks * 32 + grp * 8];
#pragma unroll
            for (int t = 0; t < 4; t++) {
                int tt = th * 4 + t;
                bh8 bb = *(const bh8*)&wblob_n1[(8 + (ks >> 1)) * 9216 +
                                                (16 * tt + lm) * WSTR + (ks & 1) * 32 +
                                                grp * 8];
                acc[t] = MFMA16(a, bb, acc[t]);
            }
        }
#pragma unroll
        for (int t = 0; t < 4; t++) {
            int c = 16 * (th * 4 + t) + lm;
#pragma unroll
            for (int i = 0; i < 4; i++) {
                int n = n0 + rg * 16 + grp * 4 + i;
                if (n < NNODE) N2out[(size_t)n * DD + c] = acc[t][i];
            }
        }
        return;
    }
    {
        const int src0[4] = {0, 1, 4, 5};
#pragma unroll
        for (int s = 0; s < 4; s++)
            for (int idx = threadIdx.x; idx < 1152; idx += 512)
                *(uint4*)&smW[s * 9216 + idx * 8] =
                    *(const uint4*)&wblob_l[src0[s] * 9216 + idx * 8];
        for (int t = threadIdx.x; t < 128; t += 512) {
            smWd1[0][t] = Wd1_l[2 * t + 0];
            smWd1[1][t] = Wd1_l[2 * t + 1];
            smWd1[2][t] = bd1_l[t];
        }
    }
    const int wave = threadIdx.x >> 6, lane = threadIdx.x & 63;
    const int grp = lane >> 4, lm = lane & 15;
    unsigned short* buf = smBuf[wave];

    while (true) {
        __syncthreads();
        if (threadIdx.x == 0) smTile = atomicAdd(ctr, 1);
        __syncthreads();
        int tile = smTile;
        if (tile >= NT_E) break;
        int j0 = tile * 256 + wave * 32;
        if (j0 >= NE) continue;

        vf4 acc[2][8];
        int hg[2][4], wg[2][4];
        float cx[2], cy[2];
#pragma unroll
        for (int rt = 0; rt < 2; rt++) {
            int r = j0 + rt * 16 + lm;
            if (r > NE - 1) r = NE - 1;
            int hr = hi_s[r], wr = wi_s[r];
            cx[rt] = actor_ctrs[hr * 2 + 0] - node_ctrs[wr * 2 + 0];
            cy[rt] = actor_ctrs[hr * 2 + 1] - node_ctrs[wr * 2 + 1];
#pragma unroll
            for (int i = 0; i < 4; i++) {
                int j = j0 + rt * 16 + grp * 4 + i;
                if (j > NE - 1) j = NE - 1;
                hg[rt][i] = hi_s[j];
                wg[rt][i] = wi_s[j];
            }
        }
        bh8 a1[2][4];
#pragma unroll
        for (int ks = 0; ks < 4; ks++) {
            float wx[8], wy[8], wb[8];
#pragma unroll
            for (int e = 0; e < 8; e++) {
                int c = ks * 32 + grp * 8 + e;
                wx[e] = smWd1[0][c];
                wy[e] = smWd1[1][c];
                wb[e] = smWd1[2][c];
            }
#pragma unroll
            for (int rt = 0; rt < 2; rt++) {
                bh8 v;
#pragma unroll
                for (int e = 0; e < 8; e++) {
                    float x = fmaf(cy[rt], wy[e], fmaf(cx[rt], wx[e], wb[e]));
                    v[e] = (short)f2bf(fmaxf(x, 0.f));
                }
                a1[rt][ks] = v;
            }
        }
        // ---- GEMM1: d0 @ Wd2^T
#pragma unroll
        for (int rt = 0; rt < 2; rt++)
#pragma unroll
            for (int t = 0; t < 8; t++) acc[rt][t] = (vf4){0.f, 0.f, 0.f, 0.f};
#pragma unroll
        for (int ks = 0; ks < 4; ks++) {
            bh8 B[8];
#pragma unroll
            for (int t = 0; t < 8; t++)
                B[t] = *(const bh8*)&smW[(ks >> 1) * 9216 + (16 * t + lm) * WSTR +
                                         (ks & 1) * 32 + grp * 8];
#pragma unroll
            for (int rt = 0; rt < 2; rt++)
#pragma unroll
                for (int t = 0; t < 8; t++) acc[rt][t] = MFMA16(a1[rt][ks], B[t], acc[rt][t]);
        }
        LGKM0();
#pragma unroll
        for (int rt = 0; rt < 2; rt++) {
            float mean[4], rs[4];
            gn_stats8(acc[rt], mean, rs);
#pragma unroll
            for (int t = 0; t < 8; t++) {
                int c = 16 * t + lm;
                float w = gnd2_w[c], b = gnd2_b[c];
#pragma unroll
                for (int i = 0; i < 4; i++) {
                    float y = (acc[rt][t][i] - mean[i]) * rs[i] * w + b;
                    buf[(rt * 16 + grp * 4 + i) * BSTR + c] = f2bf(fmaxf(y, 0.f));
                }
            }
        }
        LGKM0();
        // ---- GEMM2: d @ Wc1_d^T
#pragma unroll
        for (int rt = 0; rt < 2; rt++)
#pragma unroll
            for (int t = 0; t < 8; t++) acc[rt][t] = (vf4){0.f, 0.f, 0.f, 0.f};
#pragma unroll
        for (int ks = 0; ks < 4; ks++) {
            bh8 B[8];
#pragma unroll
            for (int t = 0; t < 8; t++)
                B[t] = *(const bh8*)&smW[(2 + (ks >> 1)) * 9216 + (16 * t + lm) * WSTR +
                                         (ks & 1) * 32 + grp * 8];
#pragma unroll
            for (int rt = 0; rt < 2; rt++) {
                bh8 a = *(const bh8*)&buf[(rt * 16 + lm) * BSTR + ks * 32 + grp * 8];
#pragma unroll
                for (int t = 0; t < 8; t++) acc[rt][t] = MFMA16(a, B[t], acc[rt][t]);
            }
        }
        // ---- add Q2[hi]+N2[wi], gn(c1)+relu in registers
#pragma unroll
        for (int rt = 0; rt < 2; rt++)
#pragma unroll
            for (int t = 0; t < 8; t++) {
                int c = 16 * t + lm;
#pragma unroll
                for (int i = 0; i < 4; i++)
                    acc[rt][t][i] +=
                        Q2[(size_t)hg[rt][i] * DD + c] + N2[(size_t)wg[rt][i] * DD + c];
            }
#pragma unroll
        for (int rt = 0; rt < 2; rt++) {
            float mean[4], rs[4];
            gn_stats8(acc[rt], mean, rs);
#pragma unroll
            for (int t = 0; t < 8; t++) {
                int c = 16 * t + lm;
                float w = gnc1_w[c], b = gnc1_b[c];
#pragma unroll
                for (int i = 0; i < 4; i++) {
                    float y = (acc[rt][t][i] - mean[i]) * rs[i] * w + b;
                    acc[rt][t][i] = fmaxf(y, 0.f);  // cf1, f32, C-layout
                }
            }
        }
        // ---- fused segmented sum of cf1 -> ssum atomics (Wc2 applied in actor)
        {
            int hrem[2][4];
#pragma unroll
            for (int rt = 0; rt < 2; rt++)
#pragma unroll
                for (int i = 0; i < 4; i++) {
                    int j = j0 + rt * 16 + grp * 4 + i;
                    hrem[rt][i] = (j < NE) ? hg[rt][i] : -1;
                }
            while (true) {
                int hmin = 0x7fffffff;
#pragma unroll
                for (int rt = 0; rt < 2; rt++)
#pragma unroll
                    for (int i = 0; i < 4; i++)
                        if (hrem[rt][i] >= 0 && hrem[rt][i] < hmin) hmin = hrem[rt][i];
                hmin = min(hmin, __shfl_xor(hmin, 16, 64));
                hmin = min(hmin, __shfl_xor(hmin, 32, 64));
                if (hmin == 0x7fffffff) break;
                float p[8];
#pragma unroll
                for (int t = 0; t < 8; t++) p[t] = 0.f;
#pragma unroll
                for (int rt = 0; rt < 2; rt++)
#pragma unroll
                    for (int i = 0; i < 4; i++)
                        if (hrem[rt][i] == hmin) {
#pragma unroll
                            for (int t = 0; t < 8; t++) p[t] += acc[rt][t][i];
                            hrem[rt][i] = -1;
                        }
#pragma unroll
                for (int t = 0; t < 8; t++) {
                    p[t] += __shfl_xor(p[t], 16, 64);
                    p[t] += __shfl_xor(p[t], 32, 64);
                }
                if (grp == 0) {
#pragma unroll
                    for (int t = 0; t < 8; t++)
                        atomicAdd(&ssum[(size_t)hmin * DD + 16 * t + lm], p[t]);
                }
            }
        }
    }
}

// =====================  ACTOR(L0) + Q2(L1), 16 rows / 64-thread block  ========
__global__ __launch_bounds__(64) void actor_q2_kernel(
    const float* __restrict__ agts, const float* __restrict__ ssum,
    const float* __restrict__ Aa, const float* __restrict__ gnn_w,
    const float* __restrict__ gnn_b, const float* __restrict__ gnl_w,
    const float* __restrict__ gnl_b, const unsigned short* __restrict__ wblob,
    float* __restrict__ A1, const float* __restrict__ gnq_w1,
    const float* __restrict__ gnq_b1, float* __restrict__ Q2) {
    __shared__ unsigned short smA[16 * ASTR];
    const int lane = threadIdx.x, grp = lane >> 4, lm = lane & 15;
    const int m0 = blockIdx.x * 16;

    stage16(ssum, m0, smA, lane);
    __syncthreads();
    vf4 acc[8];
#pragma unroll
    for (int t = 0; t < 8; t++) acc[t] = (vf4){0.f, 0.f, 0.f, 0.f};
    gemm16(smA, wblob + 10 * 9216, acc, grp, lm);  // ssum_cf1 @ Wc2^T
#pragma unroll
    for (int t = 0; t < 8; t++) {
        int c = 16 * t + lm;
#pragma unroll
        for (int i = 0; i < 4; i++)
            acc[t][i] += Aa[(size_t)(m0 + grp * 4 + i) * DD + c];  // + actors@Wa^T
    }
    __syncthreads();
    gn_to_lds<true>(acc, gnn_w, gnn_b, smA, ASTR, 0, 0, grp, lm);
    __syncthreads();
#pragma unroll
    for (int t = 0; t < 8; t++) acc[t] = (vf4){0.f, 0.f, 0.f, 0.f};
    gemm16(smA, wblob + 14 * 9216, acc, grp, lm);  // @ Wl^T
    {
        float mean[4], rs[4];
        gn_stats8(acc, mean, rs);
        __syncthreads();
#pragma unroll
        for (int t = 0; t < 8; t++) {
            int c = 16 * t + lm;
            float w = gnl_w[c], b = gnl_b[c];
#pragma unroll
            for (int i = 0; i < 4; i++) {
                int m = m0 + grp * 4 + i;
                float y = (acc[t][i] - mean[i]) * rs[i] * w + b + agts[(size_t)m * DD + c];
                float o = fmaxf(y, 0.f);
                A1[(size_t)m * DD + c] = o;
                smA[(grp * 4 + i) * ASTR + c] = f2bf(o);
            }
        }
    }
    __syncthreads();
#pragma unroll
    for (int t = 0; t < 8; t++) acc[t] = (vf4){0.f, 0.f, 0.f, 0.f};
    gemm16(smA, wblob + (16 + 2) * 9216, acc, grp, lm);
    __syncthreads();
    gn_to_lds<true>(acc, gnq_w1, gnq_b1, smA, ASTR, 0, 0, grp, lm);
    __syncthreads();
#pragma unroll
    for (int t = 0; t < 8; t++) acc[t] = (vf4){0.f, 0.f, 0.f, 0.f};
    gemm16(smA, wblob + (16 + 6) * 9216, acc, grp, lm);
#pragma unroll
    for (int t = 0; t < 8; t++) {
        int c = 16 * t + lm;
#pragma unroll
        for (int i = 0; i < 4; i++)
            Q2[(size_t)(m0 + grp * 4 + i) * DD + c] = acc[t][i];
    }
}

// =====================  ACTOR (layer 1, final), 16 rows / 64 threads  =========
__global__ __launch_bounds__(64) void actor_kernel(
    const float* __restrict__ A1, const float* __restrict__ ssum,
    const float* __restrict__ gnn_w, const float* __restrict__ gnn_b,
    const float* __restrict__ gnl_w, const float* __restrict__ gnl_b,
    const unsigned short* __restrict__ wblob_l, float* __restrict__ dst) {
    __shared__ unsigned short smA[16 * ASTR];
    const int lane = threadIdx.x, grp = lane >> 4, lm = lane & 15;
    const int m0 = blockIdx.x * 16;

    stage16(ssum, m0, smA, lane);
    __syncthreads();
    vf4 acc[8];
#pragma unroll
    for (int t = 0; t < 8; t++) acc[t] = (vf4){0.f, 0.f, 0.f, 0.f};
    gemm16(smA, wblob_l + 10 * 9216, acc, grp, lm);  // ssum_cf1 @ Wc2^T
    __syncthreads();
    stage16(A1, m0, smA, lane);
    __syncthreads();
    gemm16(smA, wblob_l + 12 * 9216, acc, grp, lm);  // + A1 @ Wa^T
    __syncthreads();
    gn_to_lds<true>(acc, gnn_w, gnn_b, smA, ASTR, 0, 0, grp, lm);
    __syncthreads();
#pragma unroll
    for (int t = 0; t < 8; t++) acc[t] = (vf4){0.f, 0.f, 0.f, 0.f};
    gemm16(smA, wblob_l + 14 * 9216, acc, grp, lm);  // @ Wl^T
    {
        float mean[4], rs[4];
        gn_stats8(acc, mean, rs);
#pragma unroll
        for (int t = 0; t < 8; t++) {
            int c = 16 * t + lm;
            float w = gnl_w[c], b = gnl_b[c];
#pragma unroll
            for (int i = 0; i < 4; i++) {
                int m = m0 + grp * 4 + i;
                float y = (acc[t][i] - mean[i]) * rs[i] * w + b + A1[(size_t)m * DD + c];
                dst[(size_t)m * DD + c] = fmaxf(y, 0.f);
            }
        }
    }
}

extern "C" void kernel_launch(void* const* d_in, const int* in_sizes, int n_in,
                              void* d_out, int out_size, void* d_ws, size_t ws_size,
                              hipStream_t stream) {
    const float* actors = (const float*)d_in[0];
    const float* nodes = (const float*)d_in[1];
    const float* actor_ctrs = (const float*)d_in[2];
    const float* node_ctrs = (const float*)d_in[3];
    const int* hi = (const int*)d_in[4];
    const int* wi = (const int*)d_in[5];
    const float* Wd1 = (const float*)d_in[6];
    const float* bd1 = (const float*)d_in[7];
    const float* Wd2 = (const float*)d_in[8];
    const float* gnd2_w = (const float*)d_in[9];
    const float* gnd2_b = (const float*)d_in[10];
    const float* Wq = (const float*)d_in[11];
    const float* gnq_w = (const float*)d_in[12];
    const float* gnq_b = (const float*)d_in[13];
    const float* Wc1 = (const float*)d_in[14];
    const float* gnc1_w = (const float*)d_in[15];
    const float* gnc1_b = (const float*)d_in[16];
    const float* Wc2 = (const float*)d_in[17];
    const float* Wa = (const float*)d_in[18];
    const float* gnn_w = (const float*)d_in[19];
    const float* gnn_b = (const float*)d_in[20];
    const float* Wl = (const float*)d_in[21];
    const float* gnl_w = (const float*)d_in[22];
    const float* gnl_b = (const float*)d_in[23];
    float* out = (float*)d_out;

    char* ws = (char*)d_ws;
    unsigned short* wblob = (unsigned short*)ws;  ws += 2 * 16 * 9216 * 2;       // 0.59 MB
    float* Q2 = (float*)ws;                       ws += (size_t)M_ACT * DD * 4;  // 2.05 MB
    float* N2_0 = (float*)ws;                     ws += (size_t)NNODE * DD * 4;  // 10.24 MB
    float* N2_1 = (float*)ws;                     ws += (size_t)NNODE * DD * 4;  // 10.24 MB
    float* A1 = (float*)ws;                       ws += (size_t)M_ACT * DD * 4;  // 2.05 MB
    float* Aa = (float*)ws;                       ws += (size_t)M_ACT * DD * 4;  // 2.05 MB
    int* cursor = (int*)ws;                       ws += M_ACT * 4;
    int* hi_s = (int*)ws;                         ws += NE * 4;
    int* wi_s = (int*)ws;                         ws += NE * 4;
    // ---- contiguous zero region: hist | ctr4 | ssum0 | ssum1 (single memset)
    char* zbase = ws;
    int* hist = (int*)ws;                         ws += M_ACT * 4;               // 16000
    int* ctr4 = (int*)ws;                         ws += 64;
    float* ssum0 = (float*)ws;                    ws += (size_t)M_ACT * DD * 4;  // 2.05 MB
    float* ssum1 = (float*)ws;                    ws += (size_t)M_ACT * DD * 4;  // 2.05 MB
    const size_t zbytes = (size_t)(ws - zbase);

    (void)hipMemsetAsync(zbase, 0, zbytes, stream);
    setup_kernel<<<HB + 32 + 2 * AB, 256, 0, stream>>>(hi, hist, Wd2, Wq, Wc1, Wc2, Wa, Wl,
                                                       wblob, actors, gnq_w, gnq_b, Q2, Aa);
    scan_kernel<<<1, 256, 0, stream>>>(hist, cursor);

    const unsigned short* wb0 = wblob;
    const unsigned short* wb1 = wblob + 16 * 9216;

    mega1_kernel<<<HB + NB_N2, 256, 0, stream>>>(hi, wi, cursor, hi_s, wi_s, nodes, wb0,
                                                 N2_0);
    // ---- layer 0 (edge grid carries N2_1 tail blocks)
    edge_kernel<<<256 + NB_N2, 512, 0, stream>>>(actor_ctrs, node_ctrs, Wd1, bd1, Q2, N2_0,
                                                 hi_s, wi_s, wb0, gnd2_w, gnd2_b, gnc1_w,
                                                 gnc1_b, ssum0, &ctr4[0], nodes, wb1, N2_1);
    actor_q2_kernel<<<AB16, 64, 0, stream>>>(actors, ssum0, Aa, gnn_w, gnn_b, gnl_w, gnl_b,
                                             wblob, A1, gnq_w + 128, gnq_b + 128, Q2);
    // ---- layer 1
    edge_kernel<<<256, 512, 0, stream>>>(actor_ctrs, node_ctrs, Wd1 + 256, bd1 + 128, Q2,
                                         N2_1, hi_s, wi_s, wb1, gnd2_w + 128, gnd2_b + 128,
                                         gnc1_w + 128, gnc1_b + 128, ssum1, &ctr4[1], nodes,
                                         wb1, N2_1);
    actor_kernel<<<AB16, 64, 0, stream>>>(A1, ssum1, gnn_w + 128, gnn_b + 128, gnl_w + 128,
                                          gnl_b + 128, wb1, out);
}

// Round 12
// 281.517 us; speedup vs baseline: 1.1290x; 1.1290x over previous
//
#include <hip/hip_runtime.h>

#define M_ACT 4000
#define NNODE 20000
#define NE 150000
#define DD 128
#define NT_E 586   // ceil(NE/256), edge kernel: 256 rank-rows per block tile
#define NB_N2 313  // ceil(NNODE/64)
#define HB 587     // ceil(NE/256), hist/scatter blocks
#define AB 63      // ceil(M_ACT/64), 64-row units
#define AB16 250   // M_ACT/16, 16-row actor blocks (exact)
#define ASTR 136   // actor LDS row stride (shorts)
#define WSTR 72    // wblob chunk row stride (shorts)
#define BSTR 136   // transpose buffer row stride (shorts): 68 words == 4 mod 32 -> conflict-free b128

typedef __attribute__((ext_vector_type(8))) short bh8;
typedef __attribute__((ext_vector_type(4))) float vf4;

#define MFMA16(a, b, c) __builtin_amdgcn_mfma_f32_16x16x32_bf16((a), (b), (c), 0, 0, 0)
#define LGKM0() __asm__ volatile("s_waitcnt lgkmcnt(0)" ::: "memory")

__device__ __forceinline__ unsigned short f2bf(float f) {
    unsigned u = __float_as_uint(f);
    u = (u + 0x7fffu + ((u >> 16) & 1u)) >> 16;
    return (unsigned short)u;
}
__device__ __forceinline__ float bf2f(unsigned short s) {
    return __uint_as_float(((unsigned)s) << 16);
}

// GroupNorm stats from one 16x128 MFMA C-layout row-tile (8 col-tiles).
__device__ __forceinline__ void gn_stats8(const vf4* acc, float* mean, float* rs) {
    float s[4], q[4];
#pragma unroll
    for (int i = 0; i < 4; i++) {
        float a = 0.f, b = 0.f;
#pragma unroll
        for (int t = 0; t < 8; t++) { float v = acc[t][i]; a += v; b += v * v; }
        s[i] = a; q[i] = b;
    }
#pragma unroll
    for (int m = 1; m < 16; m <<= 1) {
#pragma unroll
        for (int i = 0; i < 4; i++) {
            s[i] += __shfl_xor(s[i], m, 64);
            q[i] += __shfl_xor(q[i], m, 64);
        }
    }
#pragma unroll
    for (int i = 0; i < 4; i++) {
        float mu = s[i] * (1.0f / 128.0f);
        float var = q[i] * (1.0f / 128.0f) - mu * mu;
        mean[i] = mu;
        rs[i] = rsqrtf(var + 1e-5f);
    }
}

template <bool RELU>
__device__ __forceinline__ void gn_to_lds(const vf4* acc, const float* __restrict__ gw,
                                          const float* __restrict__ gb, unsigned short* sm,
                                          int stride, int cb, int r0, int grp, int lm) {
    float mean[4], rs[4];
    gn_stats8(acc, mean, rs);
#pragma unroll
    for (int t = 0; t < 8; t++) {
        int c = 16 * t + lm;
        float w = gw[c], b = gb[c];
#pragma unroll
        for (int i = 0; i < 4; i++) {
            float y = (acc[t][i] - mean[i]) * rs[i] * w + b;
            if (RELU) y = fmaxf(y, 0.0f);
            sm[(r0 + grp * 4 + i) * stride + cb + c] = f2bf(y);
        }
    }
}

__device__ __forceinline__ void load_chunk(const unsigned short* __restrict__ src,
                                           unsigned short* dst, int tid) {
    for (int idx = tid; idx < 1152; idx += 256) {
        *(uint4*)&dst[idx * 8] = *(const uint4*)&src[idx * 8];
    }
}

// 16-row GEMM pass, B-fragments streamed directly from the L2-hot wblob.
__device__ __forceinline__ void gemm16(const unsigned short* smA,
                                       const unsigned short* __restrict__ w2ch, vf4* acc,
                                       int grp, int lm) {
#pragma unroll
    for (int ks = 0; ks < 4; ks++) {
        bh8 a = *(const bh8*)&smA[lm * ASTR + ks * 32 + grp * 8];
#pragma unroll
        for (int t = 0; t < 8; t++) {
            bh8 b = *(const bh8*)&w2ch[(ks >> 1) * 9216 + (16 * t + lm) * WSTR +
                                       (ks & 1) * 32 + grp * 8];
            acc[t] = MFMA16(a, b, acc[t]);
        }
    }
}

// stage 16 rows of f32 src (rows m0..m0+15, all < M_ACT) into smA as bf16
__device__ __forceinline__ void stage16(const float* __restrict__ src, int m0,
                                        unsigned short* smA, int lane) {
    for (int idx = lane; idx < 16 * 32; idx += 64) {
        int r = idx >> 5, q = idx & 31;
        const float4 v = *(const float4*)(src + (size_t)(m0 + r) * DD + q * 4);
        unsigned lo = (unsigned)f2bf(v.x) | ((unsigned)f2bf(v.y) << 16);
        unsigned hi2 = (unsigned)f2bf(v.z) | ((unsigned)f2bf(v.w) << 16);
        *(uint2*)&smA[r * ASTR + q * 4] = make_uint2(lo, hi2);
    }
}

// q2 body: smA holds 64 rows bf16; computes relu(gn(A@Wq^T))@Wc1_q^T -> Q2.
__device__ __forceinline__ void q2_body(unsigned short* smA, unsigned short* smW,
                                        const unsigned short* __restrict__ wq,
                                        const unsigned short* __restrict__ wc,
                                        const float* __restrict__ gnq_w,
                                        const float* __restrict__ gnq_b,
                                        float* __restrict__ Q2, int m0, int tid) {
    const int wave = tid >> 6, lane = tid & 63, grp = lane >> 4, lm = lane & 15;
    const int r0 = wave * 16;
    const int arow = r0 + lm;
    vf4 acc[8];
#pragma unroll
    for (int t = 0; t < 8; t++) acc[t] = (vf4){0.f, 0.f, 0.f, 0.f};
    for (int ch = 0; ch < 2; ch++) {
        load_chunk(wq + ch * 9216, smW, tid);
        __syncthreads();
#pragma unroll
        for (int k0 = 0; k0 < 64; k0 += 32) {
            bh8 a = *(const bh8*)&smA[arow * ASTR + ch * 64 + k0 + grp * 8];
#pragma unroll
            for (int t = 0; t < 8; t++) {
                bh8 b = *(const bh8*)&smW[(16 * t + lm) * WSTR + k0 + grp * 8];
                acc[t] = MFMA16(a, b, acc[t]);
            }
        }
        __syncthreads();
    }
    gn_to_lds<true>(acc, gnq_w, gnq_b, smA, ASTR, 0, r0, grp, lm);

#pragma unroll
    for (int t = 0; t < 8; t++) acc[t] = (vf4){0.f, 0.f, 0.f, 0.f};
    for (int ch = 0; ch < 2; ch++) {
        load_chunk(wc + ch * 9216, smW, tid);
        __syncthreads();
#pragma unroll
        for (int k0 = 0; k0 < 64; k0 += 32) {
            bh8 a = *(const bh8*)&smA[arow * ASTR + ch * 64 + k0 + grp * 8];
#pragma unroll
            for (int t = 0; t < 8; t++) {
                bh8 b = *(const bh8*)&smW[(16 * t + lm) * WSTR + k0 + grp * 8];
                acc[t] = MFMA16(a, b, acc[t]);
            }
        }
        __syncthreads();
    }
#pragma unroll
    for (int t = 0; t < 8; t++) {
        int c = 16 * t + lm;
#pragma unroll
        for (int i = 0; i < 4; i++) {
            int m = m0 + r0 + grp * 4 + i;
            if (m < M_ACT) Q2[(size_t)m * DD + c] = acc[t][i];
        }
    }
}

// =====================  SETUP: hist + weight convert (merged)  ================
__global__ void setup_kernel(const int* __restrict__ hi, int* __restrict__ hist,
                             const float* __restrict__ Wd2, const float* __restrict__ Wq,
                             const float* __restrict__ Wc1, const float* __restrict__ Wc2,
                             const float* __restrict__ Wa, const float* __restrict__ Wl,
                             unsigned short* __restrict__ wblob) {
    int b = blockIdx.x;
    if (b < HB) {
        int e = b * 256 + threadIdx.x;
        if (e < NE) atomicAdd(&hist[hi[e]], 1);
        return;
    }
    int ci = b - HB;  // 0..31
    int l = ci >> 4, r = ci & 15;
    const float* src;
    int kc, K;
    if (r < 2)       { src = Wd2 + l * 16384; kc = r;      K = 128; }
    else if (r < 4)  { src = Wq  + l * 16384; kc = r - 2;  K = 128; }
    else if (r < 10) { src = Wc1 + l * 49152; kc = r - 4;  K = 384; }
    else if (r < 12) { src = Wc2 + l * 16384; kc = r - 10; K = 128; }
    else if (r < 14) { src = Wa  + l * 16384; kc = r - 12; K = 128; }
    else             { src = Wl  + l * 16384; kc = r - 14; K = 128; }
    unsigned short* dst = wblob + (size_t)ci * 9216;
    for (int idx = threadIdx.x; idx < 9216; idx += 256) {
        int n = idx / 72, kk = idx - n * 72;
        float v = (kk < 64) ? src[n * K + kc * 64 + kk] : 0.f;
        dst[idx] = f2bf(v);
    }
}

__global__ void scan_kernel(const int* __restrict__ hist, int* __restrict__ cursor) {
    __shared__ int part[256];
    int t = threadIdx.x;
    int base = t * 16;
    int s = 0;
    if (base < M_ACT)
        for (int i = 0; i < 16; i++) s += hist[base + i];
    part[t] = s;
    __syncthreads();
    for (int d = 1; d < 256; d <<= 1) {
        int u = (t >= d) ? part[t - d] : 0;
        __syncthreads();
        part[t] += u;
        __syncthreads();
    }
    int excl = part[t] - s;
    if (base < M_ACT) {
        int run = excl;
        for (int i = 0; i < 16; i++) {
            cursor[base + i] = run;
            run += hist[base + i];
        }
    }
}

// =====================  MEGA0: scatter + N2(L0) + Q2(L0) + Aa(L0)  ============
// All segments read the PRE-CONVERTED wblob (load_chunk) — round-9 proven.
// N2 layer 1 is NOT here: it rides edge0's tail blocks.
__global__ __launch_bounds__(256, 2) void mega0_kernel(
    const int* __restrict__ hi, const int* __restrict__ wi, int* __restrict__ cursor,
    int* __restrict__ hi_s, int* __restrict__ wi_s, const float* __restrict__ nodes,
    const unsigned short* __restrict__ wblob, float* __restrict__ N2_0,
    const float* __restrict__ agts, const float* __restrict__ gnq_w,
    const float* __restrict__ gnq_b, float* __restrict__ Q2, float* __restrict__ Aa) {
    __shared__ unsigned short smA[64 * ASTR];
    __shared__ unsigned short smW[128 * WSTR];
    const int tid = threadIdx.x;
    int b = blockIdx.x;
    if (b < HB) {  // ---- scatter
        int e = b * 256 + tid;
        if (e < NE) {
            int h = hi[e];
            int p = atomicAdd(&cursor[h], 1);
            hi_s[p] = h;
            wi_s[p] = wi[e];
        }
        return;
    }
    b -= HB;
    const int wave = tid >> 6, lane = tid & 63, grp = lane >> 4, lm = lane & 15;
    const int r0 = wave * 16;
    const int arow = r0 + lm;
    if (b < NB_N2) {  // ---- N2_0 = nodes @ Wc1_n^T (layer 0)
        const int n0 = b * 64;
        for (int idx = tid; idx < 64 * 32; idx += 256) {
            int r = idx >> 5, q = idx & 31;
            int n = n0 + r;
            if (n >= NNODE) n = 0;
            const float4 v = *(const float4*)(nodes + (size_t)n * DD + q * 4);
            unsigned lo = (unsigned)f2bf(v.x) | ((unsigned)f2bf(v.y) << 16);
            unsigned hi2 = (unsigned)f2bf(v.z) | ((unsigned)f2bf(v.w) << 16);
            *(uint2*)&smA[r * ASTR + q * 4] = make_uint2(lo, hi2);
        }
        __syncthreads();
        vf4 acc[8];
#pragma unroll
        for (int t = 0; t < 8; t++) acc[t] = (vf4){0.f, 0.f, 0.f, 0.f};
        for (int ch = 0; ch < 2; ch++) {
            load_chunk(wblob + (8 + ch) * 9216, smW, tid);
            __syncthreads();
#pragma unroll
            for (int k0 = 0; k0 < 64; k0 += 32) {
                bh8 a = *(const bh8*)&smA[arow * ASTR + ch * 64 + k0 + grp * 8];
#pragma unroll
                for (int t = 0; t < 8; t++) {
                    bh8 bb = *(const bh8*)&smW[(16 * t + lm) * WSTR + k0 + grp * 8];
                    acc[t] = MFMA16(a, bb, acc[t]);
                }
            }
            __syncthreads();
        }
#pragma unroll
        for (int t = 0; t < 8; t++) {
            int c = 16 * t + lm;
#pragma unroll
            for (int i = 0; i < 4; i++) {
                int n = n0 + r0 + grp * 4 + i;
                if (n < NNODE) N2_0[(size_t)n * DD + c] = acc[t][i];
            }
        }
        return;
    }
    b -= NB_N2;
    // both remaining segments stage 64 rows of agts
    const int m0 = (b < AB ? b : b - AB) * 64;
    for (int idx = tid; idx < 64 * 32; idx += 256) {
        int r = idx >> 5, q = idx & 31;
        int m = m0 + r;
        if (m >= M_ACT) m = 0;
        const float4 v = *(const float4*)(agts + (size_t)m * DD + q * 4);
        unsigned lo = (unsigned)f2bf(v.x) | ((unsigned)f2bf(v.y) << 16);
        unsigned hi2 = (unsigned)f2bf(v.z) | ((unsigned)f2bf(v.w) << 16);
        *(uint2*)&smA[r * ASTR + q * 4] = make_uint2(lo, hi2);
    }
    __syncthreads();
    if (b < AB) {  // ---- Q2 layer 0 (pre-converted chunks 2,3 / 6,7)
        q2_body(smA, smW, wblob + 2 * 9216, wblob + 6 * 9216, gnq_w, gnq_b, Q2, m0, tid);
        return;
    }
    // ---- Aa = actors @ Wa^T (layer 0, pre-converted chunks 12,13)
    vf4 acc[8];
#pragma unroll
    for (int t = 0; t < 8; t++) acc[t] = (vf4){0.f, 0.f, 0.f, 0.f};
    for (int ch = 0; ch < 2; ch++) {
        load_chunk(wblob + (12 + ch) * 9216, smW, tid);
        __syncthreads();
#pragma unroll
        for (int k0 = 0; k0 < 64; k0 += 32) {
            bh8 a = *(const bh8*)&smA[arow * ASTR + ch * 64 + k0 + grp * 8];
#pragma unroll
            for (int t = 0; t < 8; t++) {
                bh8 bb = *(const bh8*)&smW[(16 * t + lm) * WSTR + k0 + grp * 8];
                acc[t] = MFMA16(a, bb, acc[t]);
            }
        }
        __syncthreads();
    }
#pragma unroll
    for (int t = 0; t < 8; t++) {
        int c = 16 * t + lm;
#pragma unroll
        for (int i = 0; i < 4; i++) {
            int m = m0 + r0 + grp * 4 + i;
            if (m < M_ACT) Aa[(size_t)m * DD + c] = acc[t][i];
        }
    }
}

// =====================  EDGE KERNEL (+ N2_1 tail blocks in edge0 launch)  =====
// Blocks 0..255: the proven edge path (unchanged). Blocks 256+ (only present in
// the layer-0 launch): N2_1 = nodes @ Wc1_n1^T with B streamed from the L2-hot
// wblob — they fill the edge block-drain tail instead of pre-edge serial time.
__global__ __launch_bounds__(512, 2) void edge_kernel(
    const float* __restrict__ actor_ctrs, const float* __restrict__ node_ctrs,
    const float* __restrict__ Wd1_l, const float* __restrict__ bd1_l,
    const float* __restrict__ Q2, const float* __restrict__ N2,
    const int* __restrict__ hi_s, const int* __restrict__ wi_s,
    const unsigned short* __restrict__ wblob_l,
    const float* __restrict__ gnd2_w, const float* __restrict__ gnd2_b,
    const float* __restrict__ gnc1_w, const float* __restrict__ gnc1_b,
    float* __restrict__ ssum, int* __restrict__ ctr, const float* __restrict__ nodes,
    const unsigned short* __restrict__ wblob_n1, float* __restrict__ N2out) {
    __shared__ unsigned short smW[4 * 9216];     // Wd2 k0,k1 | Wc1_d k0,k1
    __shared__ unsigned short smBuf[8][32 * BSTR];
    __shared__ float smWd1[3][128];
    __shared__ int smTile;
    if (blockIdx.x >= 256) {
        // ---- N2_1 tail block: 64 rows, 8 waves = 4 row-groups x 2 col-halves
        unsigned short* smA2 = &smBuf[0][0];
        const int tid = threadIdx.x;
        const int n0 = (blockIdx.x - 256) * 64;
        for (int idx = tid; idx < 64 * 32; idx += 512) {
            int r = idx >> 5, q = idx & 31;
            int n = n0 + r;
            if (n >= NNODE) n = 0;
            const float4 v = *(const float4*)(nodes + (size_t)n * DD + q * 4);
            unsigned lo = (unsigned)f2bf(v.x) | ((unsigned)f2bf(v.y) << 16);
            unsigned hi2 = (unsigned)f2bf(v.z) | ((unsigned)f2bf(v.w) << 16);
            *(uint2*)&smA2[r * BSTR + q * 4] = make_uint2(lo, hi2);
        }
        __syncthreads();
        const int wv = tid >> 6, lane = tid & 63, grp = lane >> 4, lm = lane & 15;
        const int rg = wv >> 1, th = wv & 1;
        vf4 acc[4];
#pragma unroll
        for (int t = 0; t < 4; t++) acc[t] = (vf4){0.f, 0.f, 0.f, 0.f};
#pragma unroll
        for (int ks = 0; ks < 4; ks++) {
            bh8 a = *(const bh8*)&smA2[(rg * 16 + lm) * BSTR + ks * 32 + grp * 8];
#pragma unroll
            for (int t = 0; t < 4; t++) {
                int tt = th * 4 + t;
                bh8 bb = *(const bh8*)&wblob_n1[(8 + (ks >> 1)) * 9216 +
                                                (16 * tt + lm) * WSTR + (ks & 1) * 32 +
                                                grp * 8];
                acc[t] = MFMA16(a, bb, acc[t]);
            }
        }
#pragma unroll
        for (int t = 0; t < 4; t++) {
            int c = 16 * (th * 4 + t) + lm;
#pragma unroll
            for (int i = 0; i < 4; i++) {
                int n = n0 + rg * 16 + grp * 4 + i;
                if (n < NNODE) N2out[(size_t)n * DD + c] = acc[t][i];
            }
        }
        return;
    }
    {
        const int src0[4] = {0, 1, 4, 5};
#pragma unroll
        for (int s = 0; s < 4; s++)
            for (int idx = threadIdx.x; idx < 1152; idx += 512)
                *(uint4*)&smW[s * 9216 + idx * 8] =
                    *(const uint4*)&wblob_l[src0[s] * 9216 + idx * 8];
        for (int t = threadIdx.x; t < 128; t += 512) {
            smWd1[0][t] = Wd1_l[2 * t + 0];
            smWd1[1][t] = Wd1_l[2 * t + 1];
            smWd1[2][t] = bd1_l[t];
        }
    }
    const int wave = threadIdx.x >> 6, lane = threadIdx.x & 63;
    const int grp = lane >> 4, lm = lane & 15;
    unsigned short* buf = smBuf[wave];

    while (true) {
        __syncthreads();
        if (threadIdx.x == 0) smTile = atomicAdd(ctr, 1);
        __syncthreads();
        int tile = smTile;
        if (tile >= NT_E) break;
        int j0 = tile * 256 + wave * 32;
        if (j0 >= NE) continue;

        vf4 acc[2][8];
        int hg[2][4], wg[2][4];
        float cx[2], cy[2];
#pragma unroll
        for (int rt = 0; rt < 2; rt++) {
            int r = j0 + rt * 16 + lm;
            if (r > NE - 1) r = NE - 1;
            int hr = hi_s[r], wr = wi_s[r];
            cx[rt] = actor_ctrs[hr * 2 + 0] - node_ctrs[wr * 2 + 0];
            cy[rt] = actor_ctrs[hr * 2 + 1] - node_ctrs[wr * 2 + 1];
#pragma unroll
            for (int i = 0; i < 4; i++) {
                int j = j0 + rt * 16 + grp * 4 + i;
                if (j > NE - 1) j = NE - 1;
                hg[rt][i] = hi_s[j];
                wg[rt][i] = wi_s[j];
            }
        }
        bh8 a1[2][4];
#pragma unroll
        for (int ks = 0; ks < 4; ks++) {
            float wx[8], wy[8], wb[8];
#pragma unroll
            for (int e = 0; e < 8; e++) {
                int c = ks * 32 + grp * 8 + e;
                wx[e] = smWd1[0][c];
                wy[e] = smWd1[1][c];
                wb[e] = smWd1[2][c];
            }
#pragma unroll
            for (int rt = 0; rt < 2; rt++) {
                bh8 v;
#pragma unroll
                for (int e = 0; e < 8; e++) {
                    float x = fmaf(cy[rt], wy[e], fmaf(cx[rt], wx[e], wb[e]));
                    v[e] = (short)f2bf(fmaxf(x, 0.f));
                }
                a1[rt][ks] = v;
            }
        }
        // ---- GEMM1: d0 @ Wd2^T
#pragma unroll
        for (int rt = 0; rt < 2; rt++)
#pragma unroll
            for (int t = 0; t < 8; t++) acc[rt][t] = (vf4){0.f, 0.f, 0.f, 0.f};
#pragma unroll
        for (int ks = 0; ks < 4; ks++) {
            bh8 B[8];
#pragma unroll
            for (int t = 0; t < 8; t++)
                B[t] = *(const bh8*)&smW[(ks >> 1) * 9216 + (16 * t + lm) * WSTR +
                                         (ks & 1) * 32 + grp * 8];
#pragma unroll
            for (int rt = 0; rt < 2; rt++)
#pragma unroll
                for (int t = 0; t < 8; t++) acc[rt][t] = MFMA16(a1[rt][ks], B[t], acc[rt][t]);
        }
        LGKM0();
#pragma unroll
        for (int rt = 0; rt < 2; rt++) {
            float mean[4], rs[4];
            gn_stats8(acc[rt], mean, rs);
#pragma unroll
            for (int t = 0; t < 8; t++) {
                int c = 16 * t + lm;
                float w = gnd2_w[c], b = gnd2_b[c];
#pragma unroll
                for (int i = 0; i < 4; i++) {
                    float y = (acc[rt][t][i] - mean[i]) * rs[i] * w + b;
                    buf[(rt * 16 + grp * 4 + i) * BSTR + c] = f2bf(fmaxf(y, 0.f));
                }
            }
        }
        LGKM0();
        // ---- GEMM2: d @ Wc1_d^T
#pragma unroll
        for (int rt = 0; rt < 2; rt++)
#pragma unroll
            for (int t = 0; t < 8; t++) acc[rt][t] = (vf4){0.f, 0.f, 0.f, 0.f};
#pragma unroll
        for (int ks = 0; ks < 4; ks++) {
            bh8 B[8];
#pragma unroll
            for (int t = 0; t < 8; t++)
                B[t] = *(const bh8*)&smW[(2 + (ks >> 1)) * 9216 + (16 * t + lm) * WSTR +
                                         (ks & 1) * 32 + grp * 8];
#pragma unroll
            for (int rt = 0; rt < 2; rt++) {
                bh8 a = *(const bh8*)&buf[(rt * 16 + lm) * BSTR + ks * 32 + grp * 8];
#pragma unroll
                for (int t = 0; t < 8; t++) acc[rt][t] = MFMA16(a, B[t], acc[rt][t]);
            }
        }
        // ---- add Q2[hi]+N2[wi], gn(c1)+relu in registers
#pragma unroll
        for (int rt = 0; rt < 2; rt++)
#pragma unroll
            for (int t = 0; t < 8; t++) {
                int c = 16 * t + lm;
#pragma unroll
                for (int i = 0; i < 4; i++)
                    acc[rt][t][i] +=
                        Q2[(size_t)hg[rt][i] * DD + c] + N2[(size_t)wg[rt][i] * DD + c];
            }
#pragma unroll
        for (int rt = 0; rt < 2; rt++) {
            float mean[4], rs[4];
            gn_stats8(acc[rt], mean, rs);
#pragma unroll
            for (int t = 0; t < 8; t++) {
                int c = 16 * t + lm;
                float w = gnc1_w[c], b = gnc1_b[c];
#pragma unroll
                for (int i = 0; i < 4; i++) {
                    float y = (acc[rt][t][i] - mean[i]) * rs[i] * w + b;
                    acc[rt][t][i] = fmaxf(y, 0.f);  // cf1, f32, C-layout
                }
            }
        }
        // ---- fused segmented sum of cf1 -> ssum atomics (Wc2 applied in actor)
        {
            int hrem[2][4];
#pragma unroll
            for (int rt = 0; rt < 2; rt++)
#pragma unroll
                for (int i = 0; i < 4; i++) {
                    int j = j0 + rt * 16 + grp * 4 + i;
                    hrem[rt][i] = (j < NE) ? hg[rt][i] : -1;
                }
            while (true) {
                int hmin = 0x7fffffff;
#pragma unroll
                for (int rt = 0; rt < 2; rt++)
#pragma unroll
                    for (int i = 0; i < 4; i++)
                        if (hrem[rt][i] >= 0 && hrem[rt][i] < hmin) hmin = hrem[rt][i];
                hmin = min(hmin, __shfl_xor(hmin, 16, 64));
                hmin = min(hmin, __shfl_xor(hmin, 32, 64));
                if (hmin == 0x7fffffff) break;
                float p[8];
#pragma unroll
                for (int t = 0; t < 8; t++) p[t] = 0.f;
#pragma unroll
                for (int rt = 0; rt < 2; rt++)
#pragma unroll
                    for (int i = 0; i < 4; i++)
                        if (hrem[rt][i] == hmin) {
#pragma unroll
                            for (int t = 0; t < 8; t++) p[t] += acc[rt][t][i];
                            hrem[rt][i] = -1;
                        }
#pragma unroll
                for (int t = 0; t < 8; t++) {
                    p[t] += __shfl_xor(p[t], 16, 64);
                    p[t] += __shfl_xor(p[t], 32, 64);
                }
                if (grp == 0) {
#pragma unroll
                    for (int t = 0; t < 8; t++)
                        atomicAdd(&ssum[(size_t)hmin * DD + 16 * t + lm], p[t]);
                }
            }
        }
    }
}

// =====================  ACTOR(L0) + Q2(L1), 16 rows / 64-thread block  ========
__global__ __launch_bounds__(64) void actor_q2_kernel(
    const float* __restrict__ agts, const float* __restrict__ ssum,
    const float* __restrict__ Aa, const float* __restrict__ gnn_w,
    const float* __restrict__ gnn_b, const float* __restrict__ gnl_w,
    const float* __restrict__ gnl_b, const unsigned short* __restrict__ wblob,
    float* __restrict__ A1, const float* __restrict__ gnq_w1,
    const float* __restrict__ gnq_b1, float* __restrict__ Q2) {
    __shared__ unsigned short smA[16 * ASTR];
    const int lane = threadIdx.x, grp = lane >> 4, lm = lane & 15;
    const int m0 = blockIdx.x * 16;

    stage16(ssum, m0, smA, lane);
    __syncthreads();
    vf4 acc[8];
#pragma unroll
    for (int t = 0; t < 8; t++) acc[t] = (vf4){0.f, 0.f, 0.f, 0.f};
    gemm16(smA, wblob + 10 * 9216, acc, grp, lm);  // ssum_cf1 @ Wc2^T
#pragma unroll
    for (int t = 0; t < 8; t++) {
        int c = 16 * t + lm;
#pragma unroll
        for (int i = 0; i < 4; i++)
            acc[t][i] += Aa[(size_t)(m0 + grp * 4 + i) * DD + c];  // + actors@Wa^T
    }
    __syncthreads();
    gn_to_lds<true>(acc, gnn_w, gnn_b, smA, ASTR, 0, 0, grp, lm);
    __syncthreads();
#pragma unroll
    for (int t = 0; t < 8; t++) acc[t] = (vf4){0.f, 0.f, 0.f, 0.f};
    gemm16(smA, wblob + 14 * 9216, acc, grp, lm);  // @ Wl^T
    {
        float mean[4], rs[4];
        gn_stats8(acc, mean, rs);
        __syncthreads();
#pragma unroll
        for (int t = 0; t < 8; t++) {
            int c = 16 * t + lm;
            float w = gnl_w[c], b = gnl_b[c];
#pragma unroll
            for (int i = 0; i < 4; i++) {
                int m = m0 + grp * 4 + i;
                float y = (acc[t][i] - mean[i]) * rs[i] * w + b + agts[(size_t)m * DD + c];
                float o = fmaxf(y, 0.f);
                A1[(size_t)m * DD + c] = o;
                smA[(grp * 4 + i) * ASTR + c] = f2bf(o);
            }
        }
    }
    __syncthreads();
#pragma unroll
    for (int t = 0; t < 8; t++) acc[t] = (vf4){0.f, 0.f, 0.f, 0.f};
    gemm16(smA, wblob + (16 + 2) * 9216, acc, grp, lm);
    __syncthreads();
    gn_to_lds<true>(acc, gnq_w1, gnq_b1, smA, ASTR, 0, 0, grp, lm);
    __syncthreads();
#pragma unroll
    for (int t = 0; t < 8; t++) acc[t] = (vf4){0.f, 0.f, 0.f, 0.f};
    gemm16(smA, wblob + (16 + 6) * 9216, acc, grp, lm);
#pragma unroll
    for (int t = 0; t < 8; t++) {
        int c = 16 * t + lm;
#pragma unroll
        for (int i = 0; i < 4; i++)
            Q2[(size_t)(m0 + grp * 4 + i) * DD + c] = acc[t][i];
    }
}

// =====================  ACTOR (layer 1, final), 16 rows / 64 threads  =========
__global__ __launch_bounds__(64) void actor_kernel(
    const float* __restrict__ A1, const float* __restrict__ ssum,
    const float* __restrict__ gnn_w, const float* __restrict__ gnn_b,
    const float* __restrict__ gnl_w, const float* __restrict__ gnl_b,
    const unsigned short* __restrict__ wblob_l, float* __restrict__ dst) {
    __shared__ unsigned short smA[16 * ASTR];
    const int lane = threadIdx.x, grp = lane >> 4, lm = lane & 15;
    const int m0 = blockIdx.x * 16;

    stage16(ssum, m0, smA, lane);
    __syncthreads();
    vf4 acc[8];
#pragma unroll
    for (int t = 0; t < 8; t++) acc[t] = (vf4){0.f, 0.f, 0.f, 0.f};
    gemm16(smA, wblob_l + 10 * 9216, acc, grp, lm);  // ssum_cf1 @ Wc2^T
    __syncthreads();
    stage16(A1, m0, smA, lane);
    __syncthreads();
    gemm16(smA, wblob_l + 12 * 9216, acc, grp, lm);  // + A1 @ Wa^T
    __syncthreads();
    gn_to_lds<true>(acc, gnn_w, gnn_b, smA, ASTR, 0, 0, grp, lm);
    __syncthreads();
#pragma unroll
    for (int t = 0; t < 8; t++) acc[t] = (vf4){0.f, 0.f, 0.f, 0.f};
    gemm16(smA, wblob_l + 14 * 9216, acc, grp, lm);  // @ Wl^T
    {
        float mean[4], rs[4];
        gn_stats8(acc, mean, rs);
#pragma unroll
        for (int t = 0; t < 8; t++) {
            int c = 16 * t + lm;
            float w = gnl_w[c], b = gnl_b[c];
#pragma unroll
            for (int i = 0; i < 4; i++) {
                int m = m0 + grp * 4 + i;
                float y = (acc[t][i] - mean[i]) * rs[i] * w + b + A1[(size_t)m * DD + c];
                dst[(size_t)m * DD + c] = fmaxf(y, 0.f);
            }
        }
    }
}

extern "C" void kernel_launch(void* const* d_in, const int* in_sizes, int n_in,
                              void* d_out, int out_size, void* d_ws, size_t ws_size,
                              hipStream_t stream) {
    const float* actors = (const float*)d_in[0];
    const float* nodes = (const float*)d_in[1];
    const float* actor_ctrs = (const float*)d_in[2];
    const float* node_ctrs = (const float*)d_in[3];
    const int* hi = (const int*)d_in[4];
    const int* wi = (const int*)d_in[5];
    const float* Wd1 = (const float*)d_in[6];
    const float* bd1 = (const float*)d_in[7];
    const float* Wd2 = (const float*)d_in[8];
    const float* gnd2_w = (const float*)d_in[9];
    const float* gnd2_b = (const float*)d_in[10];
    const float* Wq = (const float*)d_in[11];
    const float* gnq_w = (const float*)d_in[12];
    const float* gnq_b = (const float*)d_in[13];
    const float* Wc1 = (const float*)d_in[14];
    const float* gnc1_w = (const float*)d_in[15];
    const float* gnc1_b = (const float*)d_in[16];
    const float* Wc2 = (const float*)d_in[17];
    const float* Wa = (const float*)d_in[18];
    const float* gnn_w = (const float*)d_in[19];
    const float* gnn_b = (const float*)d_in[20];
    const float* Wl = (const float*)d_in[21];
    const float* gnl_w = (const float*)d_in[22];
    const float* gnl_b = (const float*)d_in[23];
    float* out = (float*)d_out;

    char* ws = (char*)d_ws;
    unsigned short* wblob = (unsigned short*)ws;  ws += 2 * 16 * 9216 * 2;       // 0.59 MB
    float* Q2 = (float*)ws;                       ws += (size_t)M_ACT * DD * 4;  // 2.05 MB
    float* N2_0 = (float*)ws;                     ws += (size_t)NNODE * DD * 4;  // 10.24 MB
    float* N2_1 = (float*)ws;                     ws += (size_t)NNODE * DD * 4;  // 10.24 MB
    float* A1 = (float*)ws;                       ws += (size_t)M_ACT * DD * 4;  // 2.05 MB
    float* Aa = (float*)ws;                       ws += (size_t)M_ACT * DD * 4;  // 2.05 MB
    int* cursor = (int*)ws;                       ws += M_ACT * 4;
    int* hi_s = (int*)ws;                         ws += NE * 4;
    int* wi_s = (int*)ws;                         ws += NE * 4;
    // ---- contiguous zero region: hist | ctr4 | ssum0 | ssum1 (single memset)
    char* zbase = ws;
    int* hist = (int*)ws;                         ws += M_ACT * 4;               // 16000
    int* ctr4 = (int*)ws;                         ws += 64;
    float* ssum0 = (float*)ws;                    ws += (size_t)M_ACT * DD * 4;  // 2.05 MB
    float* ssum1 = (float*)ws;                    ws += (size_t)M_ACT * DD * 4;  // 2.05 MB
    const size_t zbytes = (size_t)(ws - zbase);

    (void)hipMemsetAsync(zbase, 0, zbytes, stream);
    setup_kernel<<<HB + 32, 256, 0, stream>>>(hi, hist, Wd2, Wq, Wc1, Wc2, Wa, Wl, wblob);
    scan_kernel<<<1, 256, 0, stream>>>(hist, cursor);

    const unsigned short* wb0 = wblob;
    const unsigned short* wb1 = wblob + 16 * 9216;

    mega0_kernel<<<HB + NB_N2 + 2 * AB, 256, 0, stream>>>(hi, wi, cursor, hi_s, wi_s, nodes,
                                                          wblob, N2_0, actors, gnq_w, gnq_b,
                                                          Q2, Aa);
    // ---- layer 0 (edge grid carries N2_1 tail blocks)
    edge_kernel<<<256 + NB_N2, 512, 0, stream>>>(actor_ctrs, node_ctrs, Wd1, bd1, Q2, N2_0,
                                                 hi_s, wi_s, wb0, gnd2_w, gnd2_b, gnc1_w,
                                                 gnc1_b, ssum0, &ctr4[0], nodes, wb1, N2_1);
    actor_q2_kernel<<<AB16, 64, 0, stream>>>(actors, ssum0, Aa, gnn_w, gnn_b, gnl_w, gnl_b,
                                             wblob, A1, gnq_w + 128, gnq_b + 128, Q2);
    // ---- layer 1
    edge_kernel<<<256, 512, 0, stream>>>(actor_ctrs, node_ctrs, Wd1 + 256, bd1 + 128, Q2,
                                         N2_1, hi_s, wi_s, wb1, gnd2_w + 128, gnd2_b + 128,
                                         gnc1_w + 128, gnc1_b + 128, ssum1, &ctr4[1], nodes,
                                         wb1, N2_1);
    actor_kernel<<<AB16, 64, 0, stream>>>(A1, ssum1, gnn_w + 128, gnn_b + 128, gnl_w + 128,
                                          gnl_b + 128, wb1, out);
}

// Round 13
// 275.792 us; speedup vs baseline: 1.1524x; 1.0208x over previous
//
#include <hip/hip_runtime.h>

#define M_ACT 4000
#define NNODE 20000
#define NE 150000
#define DD 128
#define NT_E 586   // ceil(NE/256), edge kernel: 256 rank-rows per block tile
#define NB_N2 313  // ceil(NNODE/64)
#define HB 587     // ceil(NE/256), hist/scatter blocks
#define AB 63      // ceil(M_ACT/64), 64-row units
#define AB16 250   // M_ACT/16, 16-row actor blocks (exact)
#define ASTR 136   // actor LDS row stride (shorts)
#define WSTR 72    // wblob chunk row stride (shorts)
#define BSTR 136   // transpose buffer row stride (shorts): 68 words == 4 mod 32 -> conflict-free b128

typedef __attribute__((ext_vector_type(8))) short bh8;
typedef __attribute__((ext_vector_type(4))) float vf4;

#define MFMA16(a, b, c) __builtin_amdgcn_mfma_f32_16x16x32_bf16((a), (b), (c), 0, 0, 0)
#define LGKM0() __asm__ volatile("s_waitcnt lgkmcnt(0)" ::: "memory")

__device__ __forceinline__ unsigned short f2bf(float f) {
    unsigned u = __float_as_uint(f);
    u = (u + 0x7fffu + ((u >> 16) & 1u)) >> 16;
    return (unsigned short)u;
}
__device__ __forceinline__ float bf2f(unsigned short s) {
    return __uint_as_float(((unsigned)s) << 16);
}

// GroupNorm stats from one 16x128 MFMA C-layout row-tile (8 col-tiles).
__device__ __forceinline__ void gn_stats8(const vf4* acc, float* mean, float* rs) {
    float s[4], q[4];
#pragma unroll
    for (int i = 0; i < 4; i++) {
        float a = 0.f, b = 0.f;
#pragma unroll
        for (int t = 0; t < 8; t++) { float v = acc[t][i]; a += v; b += v * v; }
        s[i] = a; q[i] = b;
    }
#pragma unroll
    for (int m = 1; m < 16; m <<= 1) {
#pragma unroll
        for (int i = 0; i < 4; i++) {
            s[i] += __shfl_xor(s[i], m, 64);
            q[i] += __shfl_xor(q[i], m, 64);
        }
    }
#pragma unroll
    for (int i = 0; i < 4; i++) {
        float mu = s[i] * (1.0f / 128.0f);
        float var = q[i] * (1.0f / 128.0f) - mu * mu;
        mean[i] = mu;
        rs[i] = rsqrtf(var + 1e-5f);
    }
}

template <bool RELU>
__device__ __forceinline__ void gn_to_lds(const vf4* acc, const float* __restrict__ gw,
                                          const float* __restrict__ gb, unsigned short* sm,
                                          int stride, int cb, int r0, int grp, int lm) {
    float mean[4], rs[4];
    gn_stats8(acc, mean, rs);
#pragma unroll
    for (int t = 0; t < 8; t++) {
        int c = 16 * t + lm;
        float w = gw[c], b = gb[c];
#pragma unroll
        for (int i = 0; i < 4; i++) {
            float y = (acc[t][i] - mean[i]) * rs[i] * w + b;
            if (RELU) y = fmaxf(y, 0.0f);
            sm[(r0 + grp * 4 + i) * stride + cb + c] = f2bf(y);
        }
    }
}

__device__ __forceinline__ void load_chunk(const unsigned short* __restrict__ src,
                                           unsigned short* dst, int tid) {
    for (int idx = tid; idx < 1152; idx += 256) {
        *(uint4*)&dst[idx * 8] = *(const uint4*)&src[idx * 8];
    }
}

// 16-row GEMM pass, B-fragments streamed directly from the L2-hot wblob.
__device__ __forceinline__ void gemm16(const unsigned short* smA,
                                       const unsigned short* __restrict__ w2ch, vf4* acc,
                                       int grp, int lm) {
#pragma unroll
    for (int ks = 0; ks < 4; ks++) {
        bh8 a = *(const bh8*)&smA[lm * ASTR + ks * 32 + grp * 8];
#pragma unroll
        for (int t = 0; t < 8; t++) {
            bh8 b = *(const bh8*)&w2ch[(ks >> 1) * 9216 + (16 * t + lm) * WSTR +
                                       (ks & 1) * 32 + grp * 8];
            acc[t] = MFMA16(a, b, acc[t]);
        }
    }
}

// stage 16 rows of f32 src (rows m0..m0+15, all < M_ACT) into smA as bf16
__device__ __forceinline__ void stage16(const float* __restrict__ src, int m0,
                                        unsigned short* smA, int lane) {
    for (int idx = lane; idx < 16 * 32; idx += 64) {
        int r = idx >> 5, q = idx & 31;
        const float4 v = *(const float4*)(src + (size_t)(m0 + r) * DD + q * 4);
        unsigned lo = (unsigned)f2bf(v.x) | ((unsigned)f2bf(v.y) << 16);
        unsigned hi2 = (unsigned)f2bf(v.z) | ((unsigned)f2bf(v.w) << 16);
        *(uint2*)&smA[r * ASTR + q * 4] = make_uint2(lo, hi2);
    }
}

// q2 body: smA holds 64 rows bf16; computes relu(gn(A@Wq^T))@Wc1_q^T -> Q2.
__device__ __forceinline__ void q2_body(unsigned short* smA, unsigned short* smW,
                                        const unsigned short* __restrict__ wq,
                                        const unsigned short* __restrict__ wc,
                                        const float* __restrict__ gnq_w,
                                        const float* __restrict__ gnq_b,
                                        float* __restrict__ Q2, int m0, int tid) {
    const int wave = tid >> 6, lane = tid & 63, grp = lane >> 4, lm = lane & 15;
    const int r0 = wave * 16;
    const int arow = r0 + lm;
    vf4 acc[8];
#pragma unroll
    for (int t = 0; t < 8; t++) acc[t] = (vf4){0.f, 0.f, 0.f, 0.f};
    for (int ch = 0; ch < 2; ch++) {
        load_chunk(wq + ch * 9216, smW, tid);
        __syncthreads();
#pragma unroll
        for (int k0 = 0; k0 < 64; k0 += 32) {
            bh8 a = *(const bh8*)&smA[arow * ASTR + ch * 64 + k0 + grp * 8];
#pragma unroll
            for (int t = 0; t < 8; t++) {
                bh8 b = *(const bh8*)&smW[(16 * t + lm) * WSTR + k0 + grp * 8];
                acc[t] = MFMA16(a, b, acc[t]);
            }
        }
        __syncthreads();
    }
    gn_to_lds<true>(acc, gnq_w, gnq_b, smA, ASTR, 0, r0, grp, lm);

#pragma unroll
    for (int t = 0; t < 8; t++) acc[t] = (vf4){0.f, 0.f, 0.f, 0.f};
    for (int ch = 0; ch < 2; ch++) {
        load_chunk(wc + ch * 9216, smW, tid);
        __syncthreads();
#pragma unroll
        for (int k0 = 0; k0 < 64; k0 += 32) {
            bh8 a = *(const bh8*)&smA[arow * ASTR + ch * 64 + k0 + grp * 8];
#pragma unroll
            for (int t = 0; t < 8; t++) {
                bh8 b = *(const bh8*)&smW[(16 * t + lm) * WSTR + k0 + grp * 8];
                acc[t] = MFMA16(a, b, acc[t]);
            }
        }
        __syncthreads();
    }
#pragma unroll
    for (int t = 0; t < 8; t++) {
        int c = 16 * t + lm;
#pragma unroll
        for (int i = 0; i < 4; i++) {
            int m = m0 + r0 + grp * 4 + i;
            if (m < M_ACT) Q2[(size_t)m * DD + c] = acc[t][i];
        }
    }
}

// =====================  SETUP: hist + weight convert (merged)  ================
__global__ void setup_kernel(const int* __restrict__ hi, int* __restrict__ hist,
                             const float* __restrict__ Wd2, const float* __restrict__ Wq,
                             const float* __restrict__ Wc1, const float* __restrict__ Wc2,
                             const float* __restrict__ Wa, const float* __restrict__ Wl,
                             unsigned short* __restrict__ wblob) {
    int b = blockIdx.x;
    if (b < HB) {
        int e = b * 256 + threadIdx.x;
        if (e < NE) atomicAdd(&hist[hi[e]], 1);
        return;
    }
    int ci = b - HB;  // 0..31
    int l = ci >> 4, r = ci & 15;
    const float* src;
    int kc, K;
    if (r < 2)       { src = Wd2 + l * 16384; kc = r;      K = 128; }
    else if (r < 4)  { src = Wq  + l * 16384; kc = r - 2;  K = 128; }
    else if (r < 10) { src = Wc1 + l * 49152; kc = r - 4;  K = 384; }
    else if (r < 12) { src = Wc2 + l * 16384; kc = r - 10; K = 128; }
    else if (r < 14) { src = Wa  + l * 16384; kc = r - 12; K = 128; }
    else             { src = Wl  + l * 16384; kc = r - 14; K = 128; }
    unsigned short* dst = wblob + (size_t)ci * 9216;
    for (int idx = threadIdx.x; idx < 9216; idx += 256) {
        int n = idx / 72, kk = idx - n * 72;
        float v = (kk < 64) ? src[n * K + kc * 64 + kk] : 0.f;
        dst[idx] = f2bf(v);
    }
}

__global__ void scan_kernel(const int* __restrict__ hist, int* __restrict__ cursor) {
    __shared__ int part[256];
    int t = threadIdx.x;
    int base = t * 16;
    int s = 0;
    if (base < M_ACT)
        for (int i = 0; i < 16; i++) s += hist[base + i];
    part[t] = s;
    __syncthreads();
    for (int d = 1; d < 256; d <<= 1) {
        int u = (t >= d) ? part[t - d] : 0;
        __syncthreads();
        part[t] += u;
        __syncthreads();
    }
    int excl = part[t] - s;
    if (base < M_ACT) {
        int run = excl;
        for (int i = 0; i < 16; i++) {
            cursor[base + i] = run;
            run += hist[base + i];
        }
    }
}

// =====================  MEGA0: scatter + N2(both) + Q2(L0) + Aa(L0)  ==========
// All four are mutually independent; merged by block range (round-9 proven).
__global__ __launch_bounds__(256, 2) void mega0_kernel(
    const int* __restrict__ hi, const int* __restrict__ wi, int* __restrict__ cursor,
    int* __restrict__ hi_s, int* __restrict__ wi_s, const float* __restrict__ nodes,
    const unsigned short* __restrict__ wblob, float* __restrict__ N2_0,
    float* __restrict__ N2_1, const float* __restrict__ agts,
    const float* __restrict__ gnq_w, const float* __restrict__ gnq_b,
    float* __restrict__ Q2, float* __restrict__ Aa) {
    __shared__ unsigned short smA[64 * ASTR];
    __shared__ unsigned short smW[128 * WSTR];
    const int tid = threadIdx.x;
    int b = blockIdx.x;
    if (b < HB) {  // ---- scatter
        int e = b * 256 + tid;
        if (e < NE) {
            int h = hi[e];
            int p = atomicAdd(&cursor[h], 1);
            hi_s[p] = h;
            wi_s[p] = wi[e];
        }
        return;
    }
    b -= HB;
    const int wave = tid >> 6, lane = tid & 63, grp = lane >> 4, lm = lane & 15;
    const int r0 = wave * 16;
    const int arow = r0 + lm;
    if (b < 2 * NB_N2) {  // ---- N2 = nodes @ Wc1_n^T (both layers)
        const int half = b / NB_N2;
        const int bx = b - half * NB_N2;
        const unsigned short* wblob_l = wblob + (size_t)half * 16 * 9216;
        float* __restrict__ N2 = half ? N2_1 : N2_0;
        const int n0 = bx * 64;
        for (int idx = tid; idx < 64 * 32; idx += 256) {
            int r = idx >> 5, q = idx & 31;
            int n = n0 + r;
            if (n >= NNODE) n = 0;
            const float4 v = *(const float4*)(nodes + (size_t)n * DD + q * 4);
            unsigned lo = (unsigned)f2bf(v.x) | ((unsigned)f2bf(v.y) << 16);
            unsigned hi2 = (unsigned)f2bf(v.z) | ((unsigned)f2bf(v.w) << 16);
            *(uint2*)&smA[r * ASTR + q * 4] = make_uint2(lo, hi2);
        }
        __syncthreads();
        vf4 acc[8];
#pragma unroll
        for (int t = 0; t < 8; t++) acc[t] = (vf4){0.f, 0.f, 0.f, 0.f};
        for (int ch = 0; ch < 2; ch++) {
            load_chunk(wblob_l + (8 + ch) * 9216, smW, tid);
            __syncthreads();
#pragma unroll
            for (int k0 = 0; k0 < 64; k0 += 32) {
                bh8 a = *(const bh8*)&smA[arow * ASTR + ch * 64 + k0 + grp * 8];
#pragma unroll
                for (int t = 0; t < 8; t++) {
                    bh8 bb = *(const bh8*)&smW[(16 * t + lm) * WSTR + k0 + grp * 8];
                    acc[t] = MFMA16(a, bb, acc[t]);
                }
            }
            __syncthreads();
        }
#pragma unroll
        for (int t = 0; t < 8; t++) {
            int c = 16 * t + lm;
#pragma unroll
            for (int i = 0; i < 4; i++) {
                int n = n0 + r0 + grp * 4 + i;
                if (n < NNODE) N2[(size_t)n * DD + c] = acc[t][i];
            }
        }
        return;
    }
    b -= 2 * NB_N2;
    // both remaining segments stage 64 rows of agts
    const int m0 = (b < AB ? b : b - AB) * 64;
    for (int idx = tid; idx < 64 * 32; idx += 256) {
        int r = idx >> 5, q = idx & 31;
        int m = m0 + r;
        if (m >= M_ACT) m = 0;
        const float4 v = *(const float4*)(agts + (size_t)m * DD + q * 4);
        unsigned lo = (unsigned)f2bf(v.x) | ((unsigned)f2bf(v.y) << 16);
        unsigned hi2 = (unsigned)f2bf(v.z) | ((unsigned)f2bf(v.w) << 16);
        *(uint2*)&smA[r * ASTR + q * 4] = make_uint2(lo, hi2);
    }
    __syncthreads();
    if (b < AB) {  // ---- Q2 layer 0
        q2_body(smA, smW, wblob + 2 * 9216, wblob + 6 * 9216, gnq_w, gnq_b, Q2, m0, tid);
        return;
    }
    // ---- Aa = actors @ Wa^T (layer 0, chunks 12,13)
    vf4 acc[8];
#pragma unroll
    for (int t = 0; t < 8; t++) acc[t] = (vf4){0.f, 0.f, 0.f, 0.f};
    for (int ch = 0; ch < 2; ch++) {
        load_chunk(wblob + (12 + ch) * 9216, smW, tid);
        __syncthreads();
#pragma unroll
        for (int k0 = 0; k0 < 64; k0 += 32) {
            bh8 a = *(const bh8*)&smA[arow * ASTR + ch * 64 + k0 + grp * 8];
#pragma unroll
            for (int t = 0; t < 8; t++) {
                bh8 bb = *(const bh8*)&smW[(16 * t + lm) * WSTR + k0 + grp * 8];
                acc[t] = MFMA16(a, bb, acc[t]);
            }
        }
        __syncthreads();
    }
#pragma unroll
    for (int t = 0; t < 8; t++) {
        int c = 16 * t + lm;
#pragma unroll
        for (int i = 0; i < 4; i++) {
            int m = m0 + r0 + grp * 4 + i;
            if (m < M_ACT) Aa[(size_t)m * DD + c] = acc[t][i];
        }
    }
}

// =====================  EDGE KERNEL (persistent, rank space)  =================
// Round-9 structure with ONE pipelining fix: GEMM2's accumulator is INITIALIZED
// with the Q2[hi]+N2[wi] gather (MFMA C-in), so the 128 gather loads issue
// before/during GEMM2's ds_read+MFMA stream instead of serially after it, and
// the separate 64-add VALU pass disappears. Same f32 math.
__global__ __launch_bounds__(512, 2) void edge_kernel(
    const float* __restrict__ actor_ctrs, const float* __restrict__ node_ctrs,
    const float* __restrict__ Wd1_l, const float* __restrict__ bd1_l,
    const float* __restrict__ Q2, const float* __restrict__ N2,
    const int* __restrict__ hi_s, const int* __restrict__ wi_s,
    const unsigned short* __restrict__ wblob_l,
    const float* __restrict__ gnd2_w, const float* __restrict__ gnd2_b,
    const float* __restrict__ gnc1_w, const float* __restrict__ gnc1_b,
    float* __restrict__ ssum, int* __restrict__ ctr) {
    __shared__ unsigned short smW[4 * 9216];     // Wd2 k0,k1 | Wc1_d k0,k1
    __shared__ unsigned short smBuf[8][32 * BSTR];
    __shared__ float smWd1[3][128];
    __shared__ int smTile;
    {
        const int src0[4] = {0, 1, 4, 5};
#pragma unroll
        for (int s = 0; s < 4; s++)
            for (int idx = threadIdx.x; idx < 1152; idx += 512)
                *(uint4*)&smW[s * 9216 + idx * 8] =
                    *(const uint4*)&wblob_l[src0[s] * 9216 + idx * 8];
        for (int t = threadIdx.x; t < 128; t += 512) {
            smWd1[0][t] = Wd1_l[2 * t + 0];
            smWd1[1][t] = Wd1_l[2 * t + 1];
            smWd1[2][t] = bd1_l[t];
        }
    }
    const int wave = threadIdx.x >> 6, lane = threadIdx.x & 63;
    const int grp = lane >> 4, lm = lane & 15;
    unsigned short* buf = smBuf[wave];

    while (true) {
        __syncthreads();
        if (threadIdx.x == 0) smTile = atomicAdd(ctr, 1);
        __syncthreads();
        int tile = smTile;
        if (tile >= NT_E) break;
        int j0 = tile * 256 + wave * 32;
        if (j0 >= NE) continue;

        vf4 acc[2][8];
        int hg[2][4], wg[2][4];
        float cx[2], cy[2];
#pragma unroll
        for (int rt = 0; rt < 2; rt++) {
            int r = j0 + rt * 16 + lm;
            if (r > NE - 1) r = NE - 1;
            int hr = hi_s[r], wr = wi_s[r];
            cx[rt] = actor_ctrs[hr * 2 + 0] - node_ctrs[wr * 2 + 0];
            cy[rt] = actor_ctrs[hr * 2 + 1] - node_ctrs[wr * 2 + 1];
#pragma unroll
            for (int i = 0; i < 4; i++) {
                int j = j0 + rt * 16 + grp * 4 + i;
                if (j > NE - 1) j = NE - 1;
                hg[rt][i] = hi_s[j];
                wg[rt][i] = wi_s[j];
            }
        }
        bh8 a1[2][4];
#pragma unroll
        for (int ks = 0; ks < 4; ks++) {
            float wx[8], wy[8], wb[8];
#pragma unroll
            for (int e = 0; e < 8; e++) {
                int c = ks * 32 + grp * 8 + e;
                wx[e] = smWd1[0][c];
                wy[e] = smWd1[1][c];
                wb[e] = smWd1[2][c];
            }
#pragma unroll
            for (int rt = 0; rt < 2; rt++) {
                bh8 v;
#pragma unroll
                for (int e = 0; e < 8; e++) {
                    float x = fmaf(cy[rt], wy[e], fmaf(cx[rt], wx[e], wb[e]));
                    v[e] = (short)f2bf(fmaxf(x, 0.f));
                }
                a1[rt][ks] = v;
            }
        }
        // ---- GEMM1: d0 @ Wd2^T
#pragma unroll
        for (int rt = 0; rt < 2; rt++)
#pragma unroll
            for (int t = 0; t < 8; t++) acc[rt][t] = (vf4){0.f, 0.f, 0.f, 0.f};
#pragma unroll
        for (int ks = 0; ks < 4; ks++) {
            bh8 B[8];
#pragma unroll
            for (int t = 0; t < 8; t++)
                B[t] = *(const bh8*)&smW[(ks >> 1) * 9216 + (16 * t + lm) * WSTR +
                                         (ks & 1) * 32 + grp * 8];
#pragma unroll
            for (int rt = 0; rt < 2; rt++)
#pragma unroll
                for (int t = 0; t < 8; t++) acc[rt][t] = MFMA16(a1[rt][ks], B[t], acc[rt][t]);
        }
        LGKM0();
#pragma unroll
        for (int rt = 0; rt < 2; rt++) {
            float mean[4], rs[4];
            gn_stats8(acc[rt], mean, rs);
#pragma unroll
            for (int t = 0; t < 8; t++) {
                int c = 16 * t + lm;
                float w = gnd2_w[c], b = gnd2_b[c];
#pragma unroll
                for (int i = 0; i < 4; i++) {
                    float y = (acc[rt][t][i] - mean[i]) * rs[i] * w + b;
                    buf[(rt * 16 + grp * 4 + i) * BSTR + c] = f2bf(fmaxf(y, 0.f));
                }
            }
        }
        LGKM0();
        // ---- GEMM2: acc init = Q2[hg]+N2[wg] gather (loads overlap the MFMAs),
        // then d @ Wc1_d^T accumulates on top via the MFMA C operand.
#pragma unroll
        for (int rt = 0; rt < 2; rt++)
#pragma unroll
            for (int t = 0; t < 8; t++) {
                int c = 16 * t + lm;
#pragma unroll
                for (int i = 0; i < 4; i++)
                    acc[rt][t][i] =
                        Q2[(size_t)hg[rt][i] * DD + c] + N2[(size_t)wg[rt][i] * DD + c];
            }
#pragma unroll
        for (int ks = 0; ks < 4; ks++) {
            bh8 B[8];
#pragma unroll
            for (int t = 0; t < 8; t++)
                B[t] = *(const bh8*)&smW[(2 + (ks >> 1)) * 9216 + (16 * t + lm) * WSTR +
                                         (ks & 1) * 32 + grp * 8];
#pragma unroll
            for (int rt = 0; rt < 2; rt++) {
                bh8 a = *(const bh8*)&buf[(rt * 16 + lm) * BSTR + ks * 32 + grp * 8];
#pragma unroll
                for (int t = 0; t < 8; t++) acc[rt][t] = MFMA16(a, B[t], acc[rt][t]);
            }
        }
        // ---- gn(c1)+relu in registers
#pragma unroll
        for (int rt = 0; rt < 2; rt++) {
            float mean[4], rs[4];
            gn_stats8(acc[rt], mean, rs);
#pragma unroll
            for (int t = 0; t < 8; t++) {
                int c = 16 * t + lm;
                float w = gnc1_w[c], b = gnc1_b[c];
#pragma unroll
                for (int i = 0; i < 4; i++) {
                    float y = (acc[rt][t][i] - mean[i]) * rs[i] * w + b;
                    acc[rt][t][i] = fmaxf(y, 0.f);  // cf1, f32, C-layout
                }
            }
        }
        // ---- fused segmented sum of cf1 -> ssum atomics (Wc2 applied in actor)
        {
            int hrem[2][4];
#pragma unroll
            for (int rt = 0; rt < 2; rt++)
#pragma unroll
                for (int i = 0; i < 4; i++) {
                    int j = j0 + rt * 16 + grp * 4 + i;
                    hrem[rt][i] = (j < NE) ? hg[rt][i] : -1;
                }
            while (true) {
                int hmin = 0x7fffffff;
#pragma unroll
                for (int rt = 0; rt < 2; rt++)
#pragma unroll
                    for (int i = 0; i < 4; i++)
                        if (hrem[rt][i] >= 0 && hrem[rt][i] < hmin) hmin = hrem[rt][i];
                hmin = min(hmin, __shfl_xor(hmin, 16, 64));
                hmin = min(hmin, __shfl_xor(hmin, 32, 64));
                if (hmin == 0x7fffffff) break;
                float p[8];
#pragma unroll
                for (int t = 0; t < 8; t++) p[t] = 0.f;
#pragma unroll
                for (int rt = 0; rt < 2; rt++)
#pragma unroll
                    for (int i = 0; i < 4; i++)
                        if (hrem[rt][i] == hmin) {
#pragma unroll
                            for (int t = 0; t < 8; t++) p[t] += acc[rt][t][i];
                            hrem[rt][i] = -1;
                        }
#pragma unroll
                for (int t = 0; t < 8; t++) {
                    p[t] += __shfl_xor(p[t], 16, 64);
                    p[t] += __shfl_xor(p[t], 32, 64);
                }
                if (grp == 0) {
#pragma unroll
                    for (int t = 0; t < 8; t++)
                        atomicAdd(&ssum[(size_t)hmin * DD + 16 * t + lm], p[t]);
                }
            }
        }
    }
}

// =====================  ACTOR(L0) + Q2(L1), 16 rows / 64-thread block  ========
__global__ __launch_bounds__(64) void actor_q2_kernel(
    const float* __restrict__ agts, const float* __restrict__ ssum,
    const float* __restrict__ Aa, const float* __restrict__ gnn_w,
    const float* __restrict__ gnn_b, const float* __restrict__ gnl_w,
    const float* __restrict__ gnl_b, const unsigned short* __restrict__ wblob,
    float* __restrict__ A1, const float* __restrict__ gnq_w1,
    const float* __restrict__ gnq_b1, float* __restrict__ Q2) {
    __shared__ unsigned short smA[16 * ASTR];
    const int lane = threadIdx.x, grp = lane >> 4, lm = lane & 15;
    const int m0 = blockIdx.x * 16;

    stage16(ssum, m0, smA, lane);
    __syncthreads();
    vf4 acc[8];
#pragma unroll
    for (int t = 0; t < 8; t++) acc[t] = (vf4){0.f, 0.f, 0.f, 0.f};
    gemm16(smA, wblob + 10 * 9216, acc, grp, lm);  // ssum_cf1 @ Wc2^T
#pragma unroll
    for (int t = 0; t < 8; t++) {
        int c = 16 * t + lm;
#pragma unroll
        for (int i = 0; i < 4; i++)
            acc[t][i] += Aa[(size_t)(m0 + grp * 4 + i) * DD + c];  // + actors@Wa^T
    }
    __syncthreads();
    gn_to_lds<true>(acc, gnn_w, gnn_b, smA, ASTR, 0, 0, grp, lm);
    __syncthreads();
#pragma unroll
    for (int t = 0; t < 8; t++) acc[t] = (vf4){0.f, 0.f, 0.f, 0.f};
    gemm16(smA, wblob + 14 * 9216, acc, grp, lm);  // @ Wl^T
    {
        float mean[4], rs[4];
        gn_stats8(acc, mean, rs);
        __syncthreads();
#pragma unroll
        for (int t = 0; t < 8; t++) {
            int c = 16 * t + lm;
            float w = gnl_w[c], b = gnl_b[c];
#pragma unroll
            for (int i = 0; i < 4; i++) {
                int m = m0 + grp * 4 + i;
                float y = (acc[t][i] - mean[i]) * rs[i] * w + b + agts[(size_t)m * DD + c];
                float o = fmaxf(y, 0.f);
                A1[(size_t)m * DD + c] = o;
                smA[(grp * 4 + i) * ASTR + c] = f2bf(o);
            }
        }
    }
    __syncthreads();
    // ---- Q2 layer 1: relu(gn(A1 @ Wq1^T)) @ Wc1_q1^T
#pragma unroll
    for (int t = 0; t < 8; t++) acc[t] = (vf4){0.f, 0.f, 0.f, 0.f};
    gemm16(smA, wblob + (16 + 2) * 9216, acc, grp, lm);
    __syncthreads();
    gn_to_lds<true>(acc, gnq_w1, gnq_b1, smA, ASTR, 0, 0, grp, lm);
    __syncthreads();
#pragma unroll
    for (int t = 0; t < 8; t++) acc[t] = (vf4){0.f, 0.f, 0.f, 0.f};
    gemm16(smA, wblob + (16 + 6) * 9216, acc, grp, lm);
#pragma unroll
    for (int t = 0; t < 8; t++) {
        int c = 16 * t + lm;
#pragma unroll
        for (int i = 0; i < 4; i++)
            Q2[(size_t)(m0 + grp * 4 + i) * DD + c] = acc[t][i];
    }
}

// =====================  ACTOR (layer 1, final), 16 rows / 64 threads  =========
__global__ __launch_bounds__(64) void actor_kernel(
    const float* __restrict__ A1, const float* __restrict__ ssum,
    const float* __restrict__ gnn_w, const float* __restrict__ gnn_b,
    const float* __restrict__ gnl_w, const float* __restrict__ gnl_b,
    const unsigned short* __restrict__ wblob_l, float* __restrict__ dst) {
    __shared__ unsigned short smA[16 * ASTR];
    const int lane = threadIdx.x, grp = lane >> 4, lm = lane & 15;
    const int m0 = blockIdx.x * 16;

    stage16(ssum, m0, smA, lane);
    __syncthreads();
    vf4 acc[8];
#pragma unroll
    for (int t = 0; t < 8; t++) acc[t] = (vf4){0.f, 0.f, 0.f, 0.f};
    gemm16(smA, wblob_l + 10 * 9216, acc, grp, lm);  // ssum_cf1 @ Wc2^T
    __syncthreads();
    stage16(A1, m0, smA, lane);
    __syncthreads();
    gemm16(smA, wblob_l + 12 * 9216, acc, grp, lm);  // + A1 @ Wa^T
    __syncthreads();
    gn_to_lds<true>(acc, gnn_w, gnn_b, smA, ASTR, 0, 0, grp, lm);
    __syncthreads();
#pragma unroll
    for (int t = 0; t < 8; t++) acc[t] = (vf4){0.f, 0.f, 0.f, 0.f};
    gemm16(smA, wblob_l + 14 * 9216, acc, grp, lm);  // @ Wl^T
    {
        float mean[4], rs[4];
        gn_stats8(acc, mean, rs);
#pragma unroll
        for (int t = 0; t < 8; t++) {
            int c = 16 * t + lm;
            float w = gnl_w[c], b = gnl_b[c];
#pragma unroll
            for (int i = 0; i < 4; i++) {
                int m = m0 + grp * 4 + i;
                float y = (acc[t][i] - mean[i]) * rs[i] * w + b + A1[(size_t)m * DD + c];
                dst[(size_t)m * DD + c] = fmaxf(y, 0.f);
            }
        }
    }
}

extern "C" void kernel_launch(void* const* d_in, const int* in_sizes, int n_in,
                              void* d_out, int out_size, void* d_ws, size_t ws_size,
                              hipStream_t stream) {
    const float* actors = (const float*)d_in[0];
    const float* nodes = (const float*)d_in[1];
    const float* actor_ctrs = (const float*)d_in[2];
    const float* node_ctrs = (const float*)d_in[3];
    const int* hi = (const int*)d_in[4];
    const int* wi = (const int*)d_in[5];
    const float* Wd1 = (const float*)d_in[6];
    const float* bd1 = (const float*)d_in[7];
    const float* Wd2 = (const float*)d_in[8];
    const float* gnd2_w = (const float*)d_in[9];
    const float* gnd2_b = (const float*)d_in[10];
    const float* Wq = (const float*)d_in[11];
    const float* gnq_w = (const float*)d_in[12];
    const float* gnq_b = (const float*)d_in[13];
    const float* Wc1 = (const float*)d_in[14];
    const float* gnc1_w = (const float*)d_in[15];
    const float* gnc1_b = (const float*)d_in[16];
    const float* Wc2 = (const float*)d_in[17];
    const float* Wa = (const float*)d_in[18];
    const float* gnn_w = (const float*)d_in[19];
    const float* gnn_b = (const float*)d_in[20];
    const float* Wl = (const float*)d_in[21];
    const float* gnl_w = (const float*)d_in[22];
    const float* gnl_b = (const float*)d_in[23];
    float* out = (float*)d_out;

    char* ws = (char*)d_ws;
    unsigned short* wblob = (unsigned short*)ws;  ws += 2 * 16 * 9216 * 2;       // 0.59 MB
    float* Q2 = (float*)ws;                       ws += (size_t)M_ACT * DD * 4;  // 2.05 MB
    float* N2_0 = (float*)ws;                     ws += (size_t)NNODE * DD * 4;  // 10.24 MB
    float* N2_1 = (float*)ws;                     ws += (size_t)NNODE * DD * 4;  // 10.24 MB
    float* A1 = (float*)ws;                       ws += (size_t)M_ACT * DD * 4;  // 2.05 MB
    float* Aa = (float*)ws;                       ws += (size_t)M_ACT * DD * 4;  // 2.05 MB
    int* cursor = (int*)ws;                       ws += M_ACT * 4;
    int* hi_s = (int*)ws;                         ws += NE * 4;
    int* wi_s = (int*)ws;                         ws += NE * 4;
    // ---- contiguous zero region: hist | ctr4 | ssum0 | ssum1 (single memset)
    char* zbase = ws;
    int* hist = (int*)ws;                         ws += M_ACT * 4;               // 16000
    int* ctr4 = (int*)ws;                         ws += 64;
    float* ssum0 = (float*)ws;                    ws += (size_t)M_ACT * DD * 4;  // 2.05 MB
    float* ssum1 = (float*)ws;                    ws += (size_t)M_ACT * DD * 4;  // 2.05 MB
    const size_t zbytes = (size_t)(ws - zbase);

    (void)hipMemsetAsync(zbase, 0, zbytes, stream);
    setup_kernel<<<HB + 32, 256, 0, stream>>>(hi, hist, Wd2, Wq, Wc1, Wc2, Wa, Wl, wblob);
    scan_kernel<<<1, 256, 0, stream>>>(hist, cursor);

    const unsigned short* wb0 = wblob;
    const unsigned short* wb1 = wblob + 16 * 9216;

    mega0_kernel<<<HB + 2 * NB_N2 + 2 * AB, 256, 0, stream>>>(hi, wi, cursor, hi_s, wi_s,
                                                              nodes, wblob, N2_0, N2_1,
                                                              actors, gnq_w, gnq_b, Q2, Aa);
    // ---- layer 0
    edge_kernel<<<256, 512, 0, stream>>>(actor_ctrs, node_ctrs, Wd1, bd1, Q2, N2_0, hi_s,
                                         wi_s, wb0, gnd2_w, gnd2_b, gnc1_w, gnc1_b, ssum0,
                                         &ctr4[0]);
    actor_q2_kernel<<<AB16, 64, 0, stream>>>(actors, ssum0, Aa, gnn_w, gnn_b, gnl_w, gnl_b,
                                             wblob, A1, gnq_w + 128, gnq_b + 128, Q2);
    // ---- layer 1
    edge_kernel<<<256, 512, 0, stream>>>(actor_ctrs, node_ctrs, Wd1 + 256, bd1 + 128, Q2,
                                         N2_1, hi_s, wi_s, wb1, gnd2_w + 128, gnd2_b + 128,
                                         gnc1_w + 128, gnc1_b + 128, ssum1, &ctr4[1]);
    actor_kernel<<<AB16, 64, 0, stream>>>(A1, ssum1, gnn_w + 128, gnn_b + 128, gnl_w + 128,
                                          gnl_b + 128, wb1, out);
}